// Round 6
// baseline (100.408 us; speedup 1.0000x reference)
//
#include <hip/hip_runtime.h>

#define N 4096
#define F 64
#define BZ 4
#define MAGIC1 0x1F2E3D4Cu
#define MAGIC2 0x5A6B7C8Du
// NEG_SLOPE = 0.2 hardcoded below.

// order-preserving float <-> uint32 mapping
__device__ __forceinline__ unsigned int f2ord(float f) {
    unsigned int u = __float_as_uint(f);
    return (u & 0x80000000u) ? ~u : (u ^ 0x80000000u);
}
__device__ __forceinline__ float ord2f(unsigned int v) {
    unsigned int b = (v & 0x80000000u) ? (v ^ 0x80000000u) : ~v;
    return __uint_as_float(b);
}

// ---------------------------------------------------------------------------
// Device-wide barrier, R5-bug-fixed: plain data stores/loads + PROPER agent
// release/acquire fences (the R5 crash was stale-poison reads because relaxed
// flags carry no cache ops on non-coherent per-XCD L2s).
//   publisher: __syncthreads (drains all waves' stores to local L2) ->
//              tid0: release fence (L2 writeback) + relaxed flag store
//   consumer:  wave0 relaxed poll (scoped atomics bypass stale cache) ->
//              acquire fence (L1/L2 invalidate) -> __syncthreads
// Requires all 256 blocks resident: grid=256 <= 256 CUs, 1024 thr, 66 KB LDS
// (proven by R1's cooperative launch passing at this geometry).
// ---------------------------------------------------------------------------
__device__ __forceinline__ void dev_barrier(unsigned* flags, unsigned magic,
                                            int bid, int tid, int wave, int lane) {
    __syncthreads();
    if (tid == 0) {
        __builtin_amdgcn_fence(__ATOMIC_RELEASE, "agent");
        __hip_atomic_store(flags + bid, magic, __ATOMIC_RELAXED,
                           __HIP_MEMORY_SCOPE_AGENT);
    }
    if (wave == 0) {
        for (;;) {
            unsigned a0 = __hip_atomic_load(flags + lane, __ATOMIC_RELAXED,
                                            __HIP_MEMORY_SCOPE_AGENT);
            unsigned a1 = __hip_atomic_load(flags + 64 + lane, __ATOMIC_RELAXED,
                                            __HIP_MEMORY_SCOPE_AGENT);
            unsigned a2 = __hip_atomic_load(flags + 128 + lane, __ATOMIC_RELAXED,
                                            __HIP_MEMORY_SCOPE_AGENT);
            unsigned a3 = __hip_atomic_load(flags + 192 + lane, __ATOMIC_RELAXED,
                                            __HIP_MEMORY_SCOPE_AGENT);
            bool ok = (a0 == magic) & (a1 == magic) & (a2 == magic) & (a3 == magic);
            if (__all(ok)) break;
            __builtin_amdgcn_s_sleep(2);
        }
        __builtin_amdgcn_fence(__ATOMIC_ACQUIRE, "agent");
    }
    __syncthreads();
    asm volatile("" ::: "memory");
}

// ---------------------------------------------------------------------------
// Single fused kernel. grid 256 x 1024, 1 block/CU.
// Phase A (bid = b*64+chunk): k/q dots for own 64 rows -> karr, qkey, kks(LDS)
//   + LDS transpose -> xT[b][f][i] (makes Phase C's gather L1-resident).
// Phase B: stage all qkey[b] (32 KB LDS), rank-count own 64 rows + fused
//   boundary count p_i = #{j: q_j < -k_i} -> q_sorted, ordidx, pA.
// Phase C (bid = b*64+f): suffix/prefix scans of e^d*x_f, e^{0.2d}*x_f (+
//   denominators) over sorted rows in LDS; per row i combine at p_i.
// LDS union: A: tile f32[64][68]@0 (17.4K) | kks@36864
//            B: qs u64[4096]@0 | pc@32768 | pc2@34816 | kks@36864 (37.1K)
//            C: SUF1@0 PRE2@16416 SUFD@32832 PRED@49248 | wt/wb@65664 (66.2K)
// ---------------------------------------------------------------------------
__global__ __launch_bounds__(1024) void fused_gat(
        const float* __restrict__ x, const float* __restrict__ wk,
        const float* __restrict__ wq, unsigned* __restrict__ flags1,
        unsigned* __restrict__ flags2, float* __restrict__ karr,
        unsigned long long* __restrict__ qkey, float* __restrict__ q_sorted,
        unsigned int* __restrict__ ordidx, int* __restrict__ pA,
        float* __restrict__ xT, float* __restrict__ out) {
    __shared__ __align__(16) char smem[66176];
    const int bid = blockIdx.x;
    const int tid = threadIdx.x;
    const int wave = tid >> 6, lane = tid & 63;
    const int b = bid >> 6, chunk = bid & 63;

    float* kks = (float*)(smem + 36864);     // [64] own-chunk k dots (A -> B)

    // flag2 hygiene: cleared before barrier-1 arrival; barrier-1 (release on
    // flags1 orders this store, acquire on poll makes it visible) gates all
    // barrier-2 polls.
    if (tid == 0)
        __hip_atomic_store(flags2 + bid, 0u, __ATOMIC_RELAXED,
                           __HIP_MEMORY_SCOPE_AGENT);

    // ---- Phase A: dots for own chunk + xT transpose -----------------------
    {
        float (*tile)[68] = (float(*)[68])smem;
        const int row = tid >> 4;            // local row 0..63
        const int fq = tid & 15;
        const int grow = (chunk << 6) + row;
        const int f0 = fq << 2;
        float4 xv = *(const float4*)(x + ((size_t)b * N + grow) * F + f0);
        float4 k4 = *(const float4*)(wk + f0);
        float4 q4 = *(const float4*)(wq + f0);
        float kk = xv.x * k4.x + xv.y * k4.y + xv.z * k4.z + xv.w * k4.w;
        float qq = xv.x * q4.x + xv.y * q4.y + xv.z * q4.z + xv.w * q4.w;
#pragma unroll
        for (int off = 1; off <= 8; off <<= 1) {
            kk += __shfl_xor(kk, off, 16);
            qq += __shfl_xor(qq, off, 16);
        }
        if (fq == 0) {
            kks[row] = kk;
            karr[b * N + grow] = kk;
            qkey[b * N + grow] = ((unsigned long long)f2ord(qq) << 32)
                               | (unsigned int)grow;
        }
        tile[f0 + 0][row] = xv.x;
        tile[f0 + 1][row] = xv.y;
        tile[f0 + 2][row] = xv.z;
        tile[f0 + 3][row] = xv.w;
        __syncthreads();
        const int fo = row;                  // feature this thread outputs
        float4 ov = *(const float4*)(&tile[fo][fq << 2]);
        *(float4*)(xT + ((size_t)(b * F + fo)) * N + (chunk << 6) + (fq << 2)) = ov;
    }
    dev_barrier(flags1, MAGIC1, bid, tid, wave, lane);

    // ---- Phase B: rank + boundary count -----------------------------------
    {
        unsigned long long* qs = (unsigned long long*)smem;          // 32 KB
        unsigned short (*pc)[64] = (unsigned short(*)[64])(smem + 32768);
        unsigned short (*pc2)[64] = (unsigned short(*)[64])(smem + 34816);
        const unsigned long long* qb = qkey + b * N;
        for (int t = tid; t < N; t += 1024) qs[t] = qb[t];
        const float kk = kks[lane];
        const unsigned int thetaOrd = f2ord(-kk);
        __syncthreads();

        const unsigned long long myKey = qs[(chunk << 6) + lane];
        int cnt = 0, cnt2 = 0;
        const ulonglong2* q2 = (const ulonglong2*)qs;
        const int s0 = wave * 128;            // ulonglong2 units
#pragma unroll 8
        for (int t2 = 0; t2 < 128; ++t2) {
            ulonglong2 v = q2[s0 + t2];       // wave-uniform broadcast read
            cnt  += (int)(v.x < myKey) + (int)(v.y < myKey);
            cnt2 += (int)((unsigned int)(v.x >> 32) < thetaOrd)
                  + (int)((unsigned int)(v.y >> 32) < thetaOrd);
        }
        pc[wave][lane]  = (unsigned short)cnt;
        pc2[wave][lane] = (unsigned short)cnt2;
        __syncthreads();

        if (wave == 0) {
            int r = 0, p = 0;
#pragma unroll
            for (int w = 0; w < 16; ++w) { r += pc[w][lane]; p += pc2[w][lane]; }
            q_sorted[b * N + r] = ord2f((unsigned int)(myKey >> 32));
            ordidx[b * N + r] = (unsigned int)(myKey & 0xFFFFFFFFu);
            pA[b * N + (chunk << 6) + lane] = p;
        }
    }
    dev_barrier(flags2, MAGIC2, bid, tid, wave, lane);

    // ---- Phase C: scans + combine (bid reinterpreted: f = bid&63) ---------
    {
        const int f = chunk;
        float* SUF1 = (float*)smem;
        float* PRE2 = (float*)(smem + 16416);
        float* SUFD = (float*)(smem + 32832);
        float* PRED = (float*)(smem + 49248);
        float* wt1  = (float*)(smem + 65664);
        float* wtd1 = (float*)(smem + 65728);
        float* wt2  = (float*)(smem + 65792);
        float* wtd2 = (float*)(smem + 65856);
        float* wb1  = (float*)(smem + 65920);
        float* wbd1 = (float*)(smem + 65984);
        float* wb2  = (float*)(smem + 66048);
        float* wbd2 = (float*)(smem + 66112);
        const int t0 = tid << 2;
        const float* qsb = q_sorted + b * N;
        const float Qmax = qsb[N - 1];

        float4 qv = *(const float4*)(qsb + t0);
        uint4 iv = *(const uint4*)(ordidx + b * N + t0);
        float qa[4] = {qv.x, qv.y, qv.z, qv.w};
        unsigned ia[4] = {iv.x & (N - 1), iv.y & (N - 1),
                          iv.z & (N - 1), iv.w & (N - 1)};  // fault guard
        float e1[4], e2[4], w1[4], w2[4];
        const float* xrow = xT + (size_t)(b * F + f) * N;   // 16 KB, L1-resident
#pragma unroll
        for (int r = 0; r < 4; ++r) {
            float d = qa[r] - Qmax;
            e1[r] = __expf(d);
            e2[r] = __expf(0.2f * d);
            float xf = xrow[ia[r]];
            w1[r] = e1[r] * xf;
            w2[r] = e2[r] * xf;
        }

        // thread-local: exclusive prefix (w2,e2), inclusive suffix (w1,e1)
        float lp2_0 = 0.f, lp2_1 = w2[0], lp2_2 = lp2_1 + w2[1], lp2_3 = lp2_2 + w2[2];
        float T2 = lp2_3 + w2[3];
        float lpd_0 = 0.f, lpd_1 = e2[0], lpd_2 = lpd_1 + e2[1], lpd_3 = lpd_2 + e2[2];
        float TD2 = lpd_3 + e2[3];
        float ls1_3 = w1[3], ls1_2 = w1[2] + ls1_3, ls1_1 = w1[1] + ls1_2, ls1_0 = w1[0] + ls1_1;
        float T1 = ls1_0;
        float lsd_3 = e1[3], lsd_2 = e1[2] + lsd_3, lsd_1 = e1[1] + lsd_2, lsd_0 = e1[0] + lsd_1;
        float TD1 = lsd_0;

        // wave-level inclusive prefix (up) and inclusive suffix (down)
        float ip2 = T2, ipd2 = TD2;
#pragma unroll
        for (int d = 1; d < 64; d <<= 1) {
            float n1 = __shfl_up(ip2, d, 64);
            float n2 = __shfl_up(ipd2, d, 64);
            if (lane >= d) { ip2 += n1; ipd2 += n2; }
        }
        float is1 = T1, isd1 = TD1;
#pragma unroll
        for (int d = 1; d < 64; d <<= 1) {
            float n1 = __shfl_down(is1, d, 64);
            float n2 = __shfl_down(isd1, d, 64);
            if (lane + d < 64) { is1 += n1; isd1 += n2; }
        }
        if (lane == 63) { wt2[wave] = ip2; wtd2[wave] = ipd2; }
        if (lane == 0)  { wt1[wave] = is1; wtd1[wave] = isd1; }
        __syncthreads();
        // wave-base scans, 16-lane-parallel
        if (wave == 0 && lane < 16) {
            float v = wt2[lane], vd = wtd2[lane];
            float s = v, sd = vd;
#pragma unroll
            for (int d = 1; d < 16; d <<= 1) {
                float n1 = __shfl_up(s, d, 64);
                float n2 = __shfl_up(sd, d, 64);
                if (lane >= d) { s += n1; sd += n2; }
            }
            wb2[lane] = s - v; wbd2[lane] = sd - vd;
            if (lane == 15) { PRE2[N] = s; PRED[N] = sd; }
        }
        if (wave == 1 && lane < 16) {
            float v = wt1[lane], vd = wtd1[lane];
            float s = v, sd = vd;
#pragma unroll
            for (int d = 1; d < 16; d <<= 1) {
                float n1 = __shfl_down(s, d, 64);
                float n2 = __shfl_down(sd, d, 64);
                if (lane + d < 16) { s += n1; sd += n2; }
            }
            wb1[lane] = s - v; wbd1[lane] = sd - vd;
            if (lane == 0) { SUF1[N] = 0.f; SUFD[N] = 0.f; }
        }
        __syncthreads();
        float bp2 = wb2[wave] + (ip2 - T2);        // exclusive prefix base
        float bpd = wbd2[wave] + (ipd2 - TD2);
        float bs1 = wb1[wave] + (is1 - T1);        // suffix base (strictly after)
        float bsd = wbd1[wave] + (isd1 - TD1);
        float4 o;
        o.x = bp2 + lp2_0; o.y = bp2 + lp2_1; o.z = bp2 + lp2_2; o.w = bp2 + lp2_3;
        *(float4*)(PRE2 + t0) = o;
        o.x = bpd + lpd_0; o.y = bpd + lpd_1; o.z = bpd + lpd_2; o.w = bpd + lpd_3;
        *(float4*)(PRED + t0) = o;
        o.x = bs1 + ls1_0; o.y = bs1 + ls1_1; o.z = bs1 + ls1_2; o.w = bs1 + ls1_3;
        *(float4*)(SUF1 + t0) = o;
        o.x = bsd + lsd_0; o.y = bsd + lsd_1; o.z = bsd + lsd_2; o.w = bsd + lsd_3;
        *(float4*)(SUFD + t0) = o;
        __syncthreads();

        // lookup: 4 original rows per thread (p precomputed in B)
        float4 kv = *(const float4*)(karr + b * N + t0);
        int4 pv = *(const int4*)(pA + b * N + t0);
        float ka[4] = {kv.x, kv.y, kv.z, kv.w};
        int pa[4] = {pv.x, pv.y, pv.z, pv.w};
        float ra[4];
#pragma unroll
        for (int r = 0; r < 4; ++r) {
            float kk = ka[r];
            int p = pa[r];
            if ((unsigned)p > N) p = N;            // fault/garbage guard
            float u = kk + Qmax;
            float M = fmaxf(u, 0.2f * u);
            float c1 = __expf(u - M);
            float c2 = __expf(0.2f * u - M);
            float num = c1 * SUF1[p] + c2 * PRE2[p];
            float den = c1 * SUFD[p] + c2 * PRED[p];
            ra[r] = num / den;
        }
        float4 res; res.x = ra[0]; res.y = ra[1]; res.z = ra[2]; res.w = ra[3];
        *(float4*)(out + ((size_t)(b * F + f)) * N + t0) = res;
    }

    // flag1 hygiene for back-to-back launches without re-poison: safe because
    // every block passed barrier-1 long before any block reaches this point.
    if (tid == 0)
        __hip_atomic_store(flags1 + bid, 0u, __ATOMIC_RELAXED,
                           __HIP_MEMORY_SCOPE_AGENT);
}

// ---------------------------------------------------------------------------
extern "C" void kernel_launch(void* const* d_in, const int* in_sizes, int n_in,
                              void* d_out, int out_size, void* d_ws, size_t ws_size,
                              hipStream_t stream) {
    const float* x  = (const float*)d_in[0];
    const float* wk = (const float*)d_in[1];
    const float* wq = (const float*)d_in[2];
    float* out = (float*)d_out;

    // ws layout (floats): flags1[256](u32) flags2[256](u32) | karr[BZ*N] |
    //   qkey(u64)[BZ*N] | q_sorted[BZ*N] | ordidx(u32)[BZ*N] | pA(i32)[BZ*N] |
    //   xT[BZ*F*N]
    float* wsf = (float*)d_ws;
    unsigned* flags1 = (unsigned*)wsf;
    unsigned* flags2 = flags1 + 256;
    float* karr = wsf + 512;
    unsigned long long* qkey = (unsigned long long*)(wsf + 512 + BZ * N);
    float* q_sorted = wsf + 512 + 3 * BZ * N;
    unsigned int* ordidx = (unsigned int*)(wsf + 512 + 4 * BZ * N);
    int* pA = (int*)(wsf + 512 + 5 * BZ * N);
    float* xT = wsf + 512 + 6 * BZ * N;

    fused_gat<<<BZ * 64, 1024, 0, stream>>>(x, wk, wq, flags1, flags2, karr,
                                            qkey, q_sorted, ordidx, pA, xT, out);
}

// Round 7
// 96.200 us; speedup vs baseline: 1.0437x; 1.0437x over previous
//
#include <hip/hip_runtime.h>

#define N 4096
#define F 64
#define BZ 4
#define MAGIC1 0x1F2E3D4Cu
#define MAGIC2 0x5A6B7C8Du
// NEG_SLOPE = 0.2 hardcoded below.

// order-preserving float <-> uint32 mapping
__device__ __forceinline__ unsigned int f2ord(float f) {
    unsigned int u = __float_as_uint(f);
    return (u & 0x80000000u) ? ~u : (u ^ 0x80000000u);
}
__device__ __forceinline__ float ord2f(unsigned int v) {
    unsigned int b = (v & 0x80000000u) ? (v ^ 0x80000000u) : ~v;
    return __uint_as_float(b);
}

// ---------------------------------------------------------------------------
// PER-BATCH device barrier (64 blocks), R6-cost-fixed. The R6 version had all
// 256 blocks x 64 lanes x 4 loads hammering 16 shared LLC lines (~15us each).
// Here: dependencies are batch-local, so each block polls only its batch's 64
// flags, ONE load per lane per round, with s_sleep backoff.
// Coherence discipline identical to R6 (verified correct there):
//   publisher: __syncthreads (drains stores) -> tid0 release fence (L2
//              writeback) + relaxed flag store
//   consumer:  wave0 relaxed poll -> acquire fence (L1/L2 inv) -> syncthreads
// Deadlock-safe: grid 256 = 256 CUs, 66KB LDS, 1024 thr -> 1 block/CU, all
// resident (placement proven by R1 cooperative launch at same geometry).
// ---------------------------------------------------------------------------
__device__ __forceinline__ void batch_barrier(unsigned* bflags, unsigned magic,
                                              int cid, int tid, int wave, int lane) {
    __syncthreads();
    if (tid == 0) {
        __builtin_amdgcn_fence(__ATOMIC_RELEASE, "agent");
        __hip_atomic_store(bflags + cid, magic, __ATOMIC_RELAXED,
                           __HIP_MEMORY_SCOPE_AGENT);
    }
    if (wave == 0) {
        for (;;) {
            unsigned a = __hip_atomic_load(bflags + lane, __ATOMIC_RELAXED,
                                           __HIP_MEMORY_SCOPE_AGENT);
            if (__all(a == magic)) break;
            __builtin_amdgcn_s_sleep(4);
        }
        __builtin_amdgcn_fence(__ATOMIC_ACQUIRE, "agent");
    }
    __syncthreads();
    asm volatile("" ::: "memory");
}

// ---------------------------------------------------------------------------
// Single fused kernel. grid 256 x 1024, 1 block/CU.
// Phase A (bid = b*64+chunk): k/q dots for own 64 rows -> karr, qkey, kks(LDS).
// Phase B: stage batch's qkey (32 KB LDS), rank-count own 64 rows + fused
//   boundary count p_i = #{j: q_j < -k_i} -> q_sorted, ordidx, pA.
// Phase C (bid = b*64+f): suffix/prefix scans of e^d*x_f, e^{0.2d}*x_f (+
//   denominators) over sorted rows in LDS; per row i combine at p_i; x gather
//   taken directly from x (L2-resident; xT transpose dropped vs R6 - it was
//   the 569K bank conflicts and most of the release-fence writeback).
// LDS union: B: qs u64[4096]@0 | pc@32768 | pc2@34816 | kks@36864 (37.1K)
//            C: SUF1@0 PRE2@16416 SUFD@32832 PRED@49248 | wt/wb@65664 (66.2K)
// ---------------------------------------------------------------------------
__global__ __launch_bounds__(1024) void fused_gat(
        const float* __restrict__ x, const float* __restrict__ wk,
        const float* __restrict__ wq, unsigned* __restrict__ flags1,
        unsigned* __restrict__ flags2, float* __restrict__ karr,
        unsigned long long* __restrict__ qkey, float* __restrict__ q_sorted,
        unsigned int* __restrict__ ordidx, int* __restrict__ pA,
        float* __restrict__ out) {
    __shared__ __align__(16) char smem[66176];
    const int bid = blockIdx.x;
    const int tid = threadIdx.x;
    const int wave = tid >> 6, lane = tid & 63;
    const int b = bid >> 6, chunk = bid & 63;
    unsigned* bf1 = flags1 + (b << 6);       // this batch's flag groups
    unsigned* bf2 = flags2 + (b << 6);

    float* kks = (float*)(smem + 36864);     // [64] own-chunk k dots (A -> B)

    // flag2 hygiene: cleared before barrier-1 arrival; barrier-1's release
    // orders the clear before flag1 publication, and its acquire on the poll
    // side makes it visible before anyone polls flags2.
    if (tid == 0)
        __hip_atomic_store(bf2 + chunk, 0u, __ATOMIC_RELAXED,
                           __HIP_MEMORY_SCOPE_AGENT);

    // ---- Phase A: dots for own chunk (16 lanes per row) -------------------
    {
        const int row = tid >> 4;            // local row 0..63
        const int fq = tid & 15;
        const int grow = (chunk << 6) + row;
        const int f0 = fq << 2;
        float4 xv = *(const float4*)(x + ((size_t)b * N + grow) * F + f0);
        float4 k4 = *(const float4*)(wk + f0);
        float4 q4 = *(const float4*)(wq + f0);
        float kk = xv.x * k4.x + xv.y * k4.y + xv.z * k4.z + xv.w * k4.w;
        float qq = xv.x * q4.x + xv.y * q4.y + xv.z * q4.z + xv.w * q4.w;
#pragma unroll
        for (int off = 1; off <= 8; off <<= 1) {
            kk += __shfl_xor(kk, off, 16);
            qq += __shfl_xor(qq, off, 16);
        }
        if (fq == 0) {
            kks[row] = kk;
            karr[b * N + grow] = kk;
            qkey[b * N + grow] = ((unsigned long long)f2ord(qq) << 32)
                               | (unsigned int)grow;
        }
    }
    batch_barrier(bf1, MAGIC1, chunk, tid, wave, lane);

    // ---- Phase B: rank + boundary count -----------------------------------
    {
        unsigned long long* qs = (unsigned long long*)smem;          // 32 KB
        unsigned short (*pc)[64] = (unsigned short(*)[64])(smem + 32768);
        unsigned short (*pc2)[64] = (unsigned short(*)[64])(smem + 34816);
        const unsigned long long* qb = qkey + b * N;
        for (int t = tid; t < N; t += 1024) qs[t] = qb[t];
        const float kk = kks[lane];
        const unsigned int thetaOrd = f2ord(-kk);
        __syncthreads();

        const unsigned long long myKey = qs[(chunk << 6) + lane];
        int cnt = 0, cnt2 = 0;
        const ulonglong2* q2 = (const ulonglong2*)qs;
        const int s0 = wave * 128;            // ulonglong2 units
#pragma unroll 8
        for (int t2 = 0; t2 < 128; ++t2) {
            ulonglong2 v = q2[s0 + t2];       // wave-uniform broadcast read
            cnt  += (int)(v.x < myKey) + (int)(v.y < myKey);
            cnt2 += (int)((unsigned int)(v.x >> 32) < thetaOrd)
                  + (int)((unsigned int)(v.y >> 32) < thetaOrd);
        }
        pc[wave][lane]  = (unsigned short)cnt;
        pc2[wave][lane] = (unsigned short)cnt2;
        __syncthreads();

        if (wave == 0) {
            int r = 0, p = 0;
#pragma unroll
            for (int w = 0; w < 16; ++w) { r += pc[w][lane]; p += pc2[w][lane]; }
            q_sorted[b * N + r] = ord2f((unsigned int)(myKey >> 32));
            ordidx[b * N + r] = (unsigned int)(myKey & 0xFFFFFFFFu);
            pA[b * N + (chunk << 6) + lane] = p;
        }
    }
    batch_barrier(bf2, MAGIC2, chunk, tid, wave, lane);

    // ---- Phase C: scans + combine (bid reinterpreted: f = bid&63) ---------
    {
        const int f = chunk;
        float* SUF1 = (float*)smem;
        float* PRE2 = (float*)(smem + 16416);
        float* SUFD = (float*)(smem + 32832);
        float* PRED = (float*)(smem + 49248);
        float* wt1  = (float*)(smem + 65664);
        float* wtd1 = (float*)(smem + 65728);
        float* wt2  = (float*)(smem + 65792);
        float* wtd2 = (float*)(smem + 65856);
        float* wb1  = (float*)(smem + 65920);
        float* wbd1 = (float*)(smem + 65984);
        float* wb2  = (float*)(smem + 66048);
        float* wbd2 = (float*)(smem + 66112);
        const int t0 = tid << 2;
        const float* qsb = q_sorted + b * N;
        const float Qmax = qsb[N - 1];

        float4 qv = *(const float4*)(qsb + t0);
        uint4 iv = *(const uint4*)(ordidx + b * N + t0);
        float qa[4] = {qv.x, qv.y, qv.z, qv.w};
        unsigned ia[4] = {iv.x & (N - 1), iv.y & (N - 1),
                          iv.z & (N - 1), iv.w & (N - 1)};  // fault guard
        float e1[4], e2[4], w1[4], w2[4];
        const float* xbf = x + (size_t)b * N * F + f;
#pragma unroll
        for (int r = 0; r < 4; ++r) {
            float d = qa[r] - Qmax;
            e1[r] = __expf(d);
            e2[r] = __expf(0.2f * d);
            float xf = xbf[(size_t)ia[r] * F];   // L2-resident gather
            w1[r] = e1[r] * xf;
            w2[r] = e2[r] * xf;
        }

        // thread-local: exclusive prefix (w2,e2), inclusive suffix (w1,e1)
        float lp2_0 = 0.f, lp2_1 = w2[0], lp2_2 = lp2_1 + w2[1], lp2_3 = lp2_2 + w2[2];
        float T2 = lp2_3 + w2[3];
        float lpd_0 = 0.f, lpd_1 = e2[0], lpd_2 = lpd_1 + e2[1], lpd_3 = lpd_2 + e2[2];
        float TD2 = lpd_3 + e2[3];
        float ls1_3 = w1[3], ls1_2 = w1[2] + ls1_3, ls1_1 = w1[1] + ls1_2, ls1_0 = w1[0] + ls1_1;
        float T1 = ls1_0;
        float lsd_3 = e1[3], lsd_2 = e1[2] + lsd_3, lsd_1 = e1[1] + lsd_2, lsd_0 = e1[0] + lsd_1;
        float TD1 = lsd_0;

        // wave-level inclusive prefix (up) and inclusive suffix (down)
        float ip2 = T2, ipd2 = TD2;
#pragma unroll
        for (int d = 1; d < 64; d <<= 1) {
            float n1 = __shfl_up(ip2, d, 64);
            float n2 = __shfl_up(ipd2, d, 64);
            if (lane >= d) { ip2 += n1; ipd2 += n2; }
        }
        float is1 = T1, isd1 = TD1;
#pragma unroll
        for (int d = 1; d < 64; d <<= 1) {
            float n1 = __shfl_down(is1, d, 64);
            float n2 = __shfl_down(isd1, d, 64);
            if (lane + d < 64) { is1 += n1; isd1 += n2; }
        }
        if (lane == 63) { wt2[wave] = ip2; wtd2[wave] = ipd2; }
        if (lane == 0)  { wt1[wave] = is1; wtd1[wave] = isd1; }
        __syncthreads();
        // wave-base scans, 16-lane-parallel
        if (wave == 0 && lane < 16) {
            float v = wt2[lane], vd = wtd2[lane];
            float s = v, sd = vd;
#pragma unroll
            for (int d = 1; d < 16; d <<= 1) {
                float n1 = __shfl_up(s, d, 64);
                float n2 = __shfl_up(sd, d, 64);
                if (lane >= d) { s += n1; sd += n2; }
            }
            wb2[lane] = s - v; wbd2[lane] = sd - vd;
            if (lane == 15) { PRE2[N] = s; PRED[N] = sd; }
        }
        if (wave == 1 && lane < 16) {
            float v = wt1[lane], vd = wtd1[lane];
            float s = v, sd = vd;
#pragma unroll
            for (int d = 1; d < 16; d <<= 1) {
                float n1 = __shfl_down(s, d, 64);
                float n2 = __shfl_down(sd, d, 64);
                if (lane + d < 16) { s += n1; sd += n2; }
            }
            wb1[lane] = s - v; wbd1[lane] = sd - vd;
            if (lane == 0) { SUF1[N] = 0.f; SUFD[N] = 0.f; }
        }
        __syncthreads();
        float bp2 = wb2[wave] + (ip2 - T2);        // exclusive prefix base
        float bpd = wbd2[wave] + (ipd2 - TD2);
        float bs1 = wb1[wave] + (is1 - T1);        // suffix base (strictly after)
        float bsd = wbd1[wave] + (isd1 - TD1);
        float4 o;
        o.x = bp2 + lp2_0; o.y = bp2 + lp2_1; o.z = bp2 + lp2_2; o.w = bp2 + lp2_3;
        *(float4*)(PRE2 + t0) = o;
        o.x = bpd + lpd_0; o.y = bpd + lpd_1; o.z = bpd + lpd_2; o.w = bpd + lpd_3;
        *(float4*)(PRED + t0) = o;
        o.x = bs1 + ls1_0; o.y = bs1 + ls1_1; o.z = bs1 + ls1_2; o.w = bs1 + ls1_3;
        *(float4*)(SUF1 + t0) = o;
        o.x = bsd + lsd_0; o.y = bsd + lsd_1; o.z = bsd + lsd_2; o.w = bsd + lsd_3;
        *(float4*)(SUFD + t0) = o;
        __syncthreads();

        // lookup: 4 original rows per thread (p precomputed in B)
        float4 kv = *(const float4*)(karr + b * N + t0);
        int4 pv = *(const int4*)(pA + b * N + t0);
        float ka[4] = {kv.x, kv.y, kv.z, kv.w};
        int pa[4] = {pv.x, pv.y, pv.z, pv.w};
        float ra[4];
#pragma unroll
        for (int r = 0; r < 4; ++r) {
            float kk = ka[r];
            int p = pa[r];
            if ((unsigned)p > N) p = N;            // fault/garbage guard
            float u = kk + Qmax;
            float M = fmaxf(u, 0.2f * u);
            float c1 = __expf(u - M);
            float c2 = __expf(0.2f * u - M);
            float num = c1 * SUF1[p] + c2 * PRE2[p];
            float den = c1 * SUFD[p] + c2 * PRED[p];
            ra[r] = num / den;
        }
        float4 res; res.x = ra[0]; res.y = ra[1]; res.z = ra[2]; res.w = ra[3];
        *(float4*)(out + ((size_t)(b * F + f)) * N + t0) = res;
    }

    // flag1 hygiene: safe, every batch block passed barrier-1 before any
    // reaches this point; flags are re-poisoned by the harness fill anyway.
    if (tid == 0)
        __hip_atomic_store(bf1 + chunk, 0u, __ATOMIC_RELAXED,
                           __HIP_MEMORY_SCOPE_AGENT);
}

// ---------------------------------------------------------------------------
extern "C" void kernel_launch(void* const* d_in, const int* in_sizes, int n_in,
                              void* d_out, int out_size, void* d_ws, size_t ws_size,
                              hipStream_t stream) {
    const float* x  = (const float*)d_in[0];
    const float* wk = (const float*)d_in[1];
    const float* wq = (const float*)d_in[2];
    float* out = (float*)d_out;

    // ws layout (floats): flags1[256](u32) flags2[256](u32) | karr[BZ*N] |
    //   qkey(u64)[BZ*N] | q_sorted[BZ*N] | ordidx(u32)[BZ*N] | pA(i32)[BZ*N]
    float* wsf = (float*)d_ws;
    unsigned* flags1 = (unsigned*)wsf;
    unsigned* flags2 = flags1 + 256;
    float* karr = wsf + 512;
    unsigned long long* qkey = (unsigned long long*)(wsf + 512 + BZ * N);
    float* q_sorted = wsf + 512 + 3 * BZ * N;
    unsigned int* ordidx = (unsigned int*)(wsf + 512 + 4 * BZ * N);
    int* pA = (int*)(wsf + 512 + 5 * BZ * N);

    fused_gat<<<BZ * 64, 1024, 0, stream>>>(x, wk, wq, flags1, flags2, karr,
                                            qkey, q_sorted, ordidx, pA, out);
}

// Round 8
// 83.543 us; speedup vs baseline: 1.2019x; 1.1515x over previous
//
#include <hip/hip_runtime.h>

#define N 4096
#define F 64
#define BZ 4
#define MAGIC1 0x1F2E3D4Cu
#define MAGIC2 0x5A6B7C8Du
// NEG_SLOPE = 0.2 hardcoded below.

#define ALOAD(p)     __hip_atomic_load((p),  __ATOMIC_RELAXED, __HIP_MEMORY_SCOPE_AGENT)
#define ASTORE(p, v) __hip_atomic_store((p), (v), __ATOMIC_RELAXED, __HIP_MEMORY_SCOPE_AGENT)

// order-preserving float <-> uint32 mapping
__device__ __forceinline__ unsigned int f2ord(float f) {
    unsigned int u = __float_as_uint(f);
    return (u & 0x80000000u) ? ~u : (u ^ 0x80000000u);
}
__device__ __forceinline__ float ord2f(unsigned int v) {
    unsigned int b = (v & 0x80000000u) ? (v ^ 0x80000000u) : ~v;
    return __uint_as_float(b);
}

// ---------------------------------------------------------------------------
// Fence-free per-batch barrier (64 blocks). R7's fences were the cost: the
// agent acquire fence invalidated all L1/L2 (FETCH 5.8->18 MB, Phase C gather
// became HBM-latency-bound) and the release fence paid a full L2 writeback.
// Here ALL cross-block data moves via agent-scope relaxed atomics (LLC is the
// single coherence point; R5-R7 proved flags via this path are never stale),
// so the barrier is ONLY flag store + poll. Normal caches stay warm for x.
// Publisher ordering: __syncthreads drains each wave's vmem (vmcnt(0)) before
// the flag store, so prior sc-stores are LLC-visible first (validated R6/R7).
// Deadlock-safe: grid 256 = 256 CUs, 1 block/CU, all resident.
// ---------------------------------------------------------------------------
__device__ __forceinline__ void batch_barrier(unsigned* bflags, unsigned magic,
                                              int cid, int tid, int wave, int lane) {
    __syncthreads();
    if (tid == 0) ASTORE(bflags + cid, magic);
    if (wave == 0) {
        for (;;) {
            unsigned a = ALOAD(bflags + lane);
            if (__all(a == magic)) break;
            __builtin_amdgcn_s_sleep(2);
        }
    }
    __syncthreads();
    asm volatile("" ::: "memory");
}

// ---------------------------------------------------------------------------
// Single fused kernel. grid 256 x 1024, 1 block/CU.
// Phase A (bid = b*64+chunk): k/q dots for own 64 rows -> qkey (agent store),
//   kks (LDS).
// Phase B: stage batch's qkey (agent loads -> 32 KB LDS), rank-count own 64
//   rows + fused boundary count p_i = #{j: q_j < -k_i}. Publish packed:
//     skey[b][r] = qbits_ord<<32 | origrow   (sorted order)
//     kp[b][i]   = kbits<<32 | p_i           (original order)
// Phase C (bid -> f = swizzled chunk): suffix/prefix scans of e^d*x_f,
//   e^{0.2d}*x_f (+denoms) over sorted rows in LDS; combine at p_i.
//   x gather via PLAIN loads (x is read-only input -> always coherent, stays
//   L2-cached). Feature swizzle f=((chunk&7)<<3)|(chunk>>3) gives each XCD a
//   contiguous 8-feature slice -> same x-lines cluster per-XCD L2.
// LDS union: B: qs u64[4096]@0 | pc@32768 | pc2@34816 | kks@36864 (37.1K)
//            C: SUF1@0 PRE2@16416 SUFD@32832 PRED@49248 | wt/wb@65664 |
//               QmaxS@66176 (66.2K)
// ---------------------------------------------------------------------------
__global__ __launch_bounds__(1024) void fused_gat(
        const float* __restrict__ x, const float* __restrict__ wk,
        const float* __restrict__ wq, unsigned* __restrict__ flags1,
        unsigned* __restrict__ flags2,
        unsigned long long* __restrict__ qkey,
        unsigned long long* __restrict__ skey,
        unsigned long long* __restrict__ kp,
        float* __restrict__ out) {
    __shared__ __align__(16) char smem[66432];
    const int bid = blockIdx.x;
    const int tid = threadIdx.x;
    const int wave = tid >> 6, lane = tid & 63;
    const int b = bid >> 6, chunk = bid & 63;
    unsigned* bf1 = flags1 + (b << 6);
    unsigned* bf2 = flags2 + (b << 6);

    float* kks = (float*)(smem + 36864);     // [64] own-chunk k dots (A -> B)

    // flag2 hygiene (for replay without re-poison): ordered before flag1 by
    // program order + vmcnt drain; barrier-1 gates all flags2 polls.
    if (tid == 0) ASTORE(bf2 + chunk, 0u);

    // ---- Phase A: dots for own chunk (16 lanes per row) -------------------
    {
        const int row = tid >> 4;            // local row 0..63
        const int fq = tid & 15;
        const int grow = (chunk << 6) + row;
        const int f0 = fq << 2;
        float4 xv = *(const float4*)(x + ((size_t)b * N + grow) * F + f0);
        float4 k4 = *(const float4*)(wk + f0);
        float4 q4 = *(const float4*)(wq + f0);
        float kk = xv.x * k4.x + xv.y * k4.y + xv.z * k4.z + xv.w * k4.w;
        float qq = xv.x * q4.x + xv.y * q4.y + xv.z * q4.z + xv.w * q4.w;
#pragma unroll
        for (int off = 1; off <= 8; off <<= 1) {
            kk += __shfl_xor(kk, off, 16);
            qq += __shfl_xor(qq, off, 16);
        }
        if (fq == 0) {
            kks[row] = kk;
            ASTORE(qkey + b * N + grow,
                   ((unsigned long long)f2ord(qq) << 32) | (unsigned int)grow);
        }
    }
    batch_barrier(bf1, MAGIC1, chunk, tid, wave, lane);

    // ---- Phase B: rank + boundary count -----------------------------------
    {
        unsigned long long* qs = (unsigned long long*)smem;          // 32 KB
        unsigned short (*pc)[64] = (unsigned short(*)[64])(smem + 32768);
        unsigned short (*pc2)[64] = (unsigned short(*)[64])(smem + 34816);
        const unsigned long long* qb = qkey + b * N;
        for (int t = tid; t < N; t += 1024) qs[t] = ALOAD(qb + t);
        const float kk = kks[lane];
        const unsigned int thetaOrd = f2ord(-kk);
        __syncthreads();

        const unsigned long long myKey = qs[(chunk << 6) + lane];
        int cnt = 0, cnt2 = 0;
        const ulonglong2* q2 = (const ulonglong2*)qs;
        const int s0 = wave * 128;            // ulonglong2 units
#pragma unroll 8
        for (int t2 = 0; t2 < 128; ++t2) {
            ulonglong2 v = q2[s0 + t2];       // wave-uniform broadcast read
            cnt  += (int)(v.x < myKey) + (int)(v.y < myKey);
            cnt2 += (int)((unsigned int)(v.x >> 32) < thetaOrd)
                  + (int)((unsigned int)(v.y >> 32) < thetaOrd);
        }
        pc[wave][lane]  = (unsigned short)cnt;
        pc2[wave][lane] = (unsigned short)cnt2;
        __syncthreads();

        if (wave == 0) {
            int r = 0, p = 0;
#pragma unroll
            for (int w = 0; w < 16; ++w) { r += pc[w][lane]; p += pc2[w][lane]; }
            ASTORE(skey + b * N + r, myKey);
            ASTORE(kp + b * N + (chunk << 6) + lane,
                   ((unsigned long long)__float_as_uint(kk) << 32)
                 | (unsigned int)p);
        }
    }
    batch_barrier(bf2, MAGIC2, chunk, tid, wave, lane);

    // ---- Phase C: scans + combine (f = swizzled chunk) --------------------
    {
        const int f = ((chunk & 7) << 3) | (chunk >> 3);   // XCD locality
        float* SUF1 = (float*)smem;
        float* PRE2 = (float*)(smem + 16416);
        float* SUFD = (float*)(smem + 32832);
        float* PRED = (float*)(smem + 49248);
        float* wt1  = (float*)(smem + 65664);
        float* wtd1 = (float*)(smem + 65728);
        float* wt2  = (float*)(smem + 65792);
        float* wtd2 = (float*)(smem + 65856);
        float* wb1  = (float*)(smem + 65920);
        float* wbd1 = (float*)(smem + 65984);
        float* wb2  = (float*)(smem + 66048);
        float* wbd2 = (float*)(smem + 66112);
        float* QmaxS = (float*)(smem + 66176);
        const int t0 = tid << 2;

        if (tid == 0)
            QmaxS[0] = ord2f((unsigned int)(ALOAD(skey + b * N + N - 1) >> 32));
        __syncthreads();
        const float Qmax = QmaxS[0];

        // per-thread 4 sorted rows (skey) + own 4 original rows (kp)
        unsigned long long sk[4], kv[4];
#pragma unroll
        for (int r = 0; r < 4; ++r) {
            sk[r] = ALOAD(skey + b * N + t0 + r);
            kv[r] = ALOAD(kp + b * N + t0 + r);
        }
        float e1[4], e2[4], w1[4], w2[4];
        const float* xbf = x + (size_t)b * N * F + f;
#pragma unroll
        for (int r = 0; r < 4; ++r) {
            float qv = ord2f((unsigned int)(sk[r] >> 32));
            unsigned ia = (unsigned int)sk[r] & (N - 1);   // fault guard
            float d = qv - Qmax;
            e1[r] = __expf(d);
            e2[r] = __expf(0.2f * d);
            float xf = xbf[(size_t)ia * F];   // plain load, L2-resident
            w1[r] = e1[r] * xf;
            w2[r] = e2[r] * xf;
        }

        // thread-local: exclusive prefix (w2,e2), inclusive suffix (w1,e1)
        float lp2_0 = 0.f, lp2_1 = w2[0], lp2_2 = lp2_1 + w2[1], lp2_3 = lp2_2 + w2[2];
        float T2 = lp2_3 + w2[3];
        float lpd_0 = 0.f, lpd_1 = e2[0], lpd_2 = lpd_1 + e2[1], lpd_3 = lpd_2 + e2[2];
        float TD2 = lpd_3 + e2[3];
        float ls1_3 = w1[3], ls1_2 = w1[2] + ls1_3, ls1_1 = w1[1] + ls1_2, ls1_0 = w1[0] + ls1_1;
        float T1 = ls1_0;
        float lsd_3 = e1[3], lsd_2 = e1[2] + lsd_3, lsd_1 = e1[1] + lsd_2, lsd_0 = e1[0] + lsd_1;
        float TD1 = lsd_0;

        // wave-level inclusive prefix (up) and inclusive suffix (down)
        float ip2 = T2, ipd2 = TD2;
#pragma unroll
        for (int d = 1; d < 64; d <<= 1) {
            float n1 = __shfl_up(ip2, d, 64);
            float n2 = __shfl_up(ipd2, d, 64);
            if (lane >= d) { ip2 += n1; ipd2 += n2; }
        }
        float is1 = T1, isd1 = TD1;
#pragma unroll
        for (int d = 1; d < 64; d <<= 1) {
            float n1 = __shfl_down(is1, d, 64);
            float n2 = __shfl_down(isd1, d, 64);
            if (lane + d < 64) { is1 += n1; isd1 += n2; }
        }
        if (lane == 63) { wt2[wave] = ip2; wtd2[wave] = ipd2; }
        if (lane == 0)  { wt1[wave] = is1; wtd1[wave] = isd1; }
        __syncthreads();
        // wave-base scans, 16-lane-parallel
        if (wave == 0 && lane < 16) {
            float v = wt2[lane], vd = wtd2[lane];
            float s = v, sd = vd;
#pragma unroll
            for (int d = 1; d < 16; d <<= 1) {
                float n1 = __shfl_up(s, d, 64);
                float n2 = __shfl_up(sd, d, 64);
                if (lane >= d) { s += n1; sd += n2; }
            }
            wb2[lane] = s - v; wbd2[lane] = sd - vd;
            if (lane == 15) { PRE2[N] = s; PRED[N] = sd; }
        }
        if (wave == 1 && lane < 16) {
            float v = wt1[lane], vd = wtd1[lane];
            float s = v, sd = vd;
#pragma unroll
            for (int d = 1; d < 16; d <<= 1) {
                float n1 = __shfl_down(s, d, 64);
                float n2 = __shfl_down(sd, d, 64);
                if (lane + d < 16) { s += n1; sd += n2; }
            }
            wb1[lane] = s - v; wbd1[lane] = sd - vd;
            if (lane == 0) { SUF1[N] = 0.f; SUFD[N] = 0.f; }
        }
        __syncthreads();
        float bp2 = wb2[wave] + (ip2 - T2);        // exclusive prefix base
        float bpd = wbd2[wave] + (ipd2 - TD2);
        float bs1 = wb1[wave] + (is1 - T1);        // suffix base (strictly after)
        float bsd = wbd1[wave] + (isd1 - TD1);
        float4 o;
        o.x = bp2 + lp2_0; o.y = bp2 + lp2_1; o.z = bp2 + lp2_2; o.w = bp2 + lp2_3;
        *(float4*)(PRE2 + t0) = o;
        o.x = bpd + lpd_0; o.y = bpd + lpd_1; o.z = bpd + lpd_2; o.w = bpd + lpd_3;
        *(float4*)(PRED + t0) = o;
        o.x = bs1 + ls1_0; o.y = bs1 + ls1_1; o.z = bs1 + ls1_2; o.w = bs1 + ls1_3;
        *(float4*)(SUF1 + t0) = o;
        o.x = bsd + lsd_0; o.y = bsd + lsd_1; o.z = bsd + lsd_2; o.w = bsd + lsd_3;
        *(float4*)(SUFD + t0) = o;
        __syncthreads();

        // lookup: 4 original rows per thread (kk, p packed in kp)
        float ra[4];
#pragma unroll
        for (int r = 0; r < 4; ++r) {
            float kk = __uint_as_float((unsigned int)(kv[r] >> 32));
            int p = (int)(kv[r] & 0xFFFFFFFFu);
            if ((unsigned)p > N) p = N;            // garbage guard
            float u = kk + Qmax;
            float M = fmaxf(u, 0.2f * u);
            float c1 = __expf(u - M);
            float c2 = __expf(0.2f * u - M);
            float num = c1 * SUF1[p] + c2 * PRE2[p];
            float den = c1 * SUFD[p] + c2 * PRED[p];
            ra[r] = num / den;
        }
        float4 res; res.x = ra[0]; res.y = ra[1]; res.z = ra[2]; res.w = ra[3];
        *(float4*)(out + ((size_t)(b * F + f)) * N + t0) = res;
    }

    // flag1 hygiene: safe, all batch blocks passed barrier-1 long before here.
    if (tid == 0) ASTORE(bf1 + chunk, 0u);
}

// ---------------------------------------------------------------------------
extern "C" void kernel_launch(void* const* d_in, const int* in_sizes, int n_in,
                              void* d_out, int out_size, void* d_ws, size_t ws_size,
                              hipStream_t stream) {
    const float* x  = (const float*)d_in[0];
    const float* wk = (const float*)d_in[1];
    const float* wq = (const float*)d_in[2];
    float* out = (float*)d_out;

    // ws layout (floats): flags1[256](u32) flags2[256](u32) |
    //   qkey(u64)[BZ*N] | skey(u64)[BZ*N] | kp(u64)[BZ*N]
    float* wsf = (float*)d_ws;
    unsigned* flags1 = (unsigned*)wsf;
    unsigned* flags2 = flags1 + 256;
    unsigned long long* qkey = (unsigned long long*)(wsf + 512);
    unsigned long long* skey = qkey + BZ * N;
    unsigned long long* kp   = skey + BZ * N;

    fused_gat<<<BZ * 64, 1024, 0, stream>>>(x, wk, wq, flags1, flags2,
                                            qkey, skey, kp, out);
}

// Round 9
// 81.587 us; speedup vs baseline: 1.2307x; 1.0240x over previous
//
#include <hip/hip_runtime.h>

#define N 4096
#define F 64
#define BZ 4
#define MAGIC1 0x1F2E3D4Cu
#define MAGIC2 0x5A6B7C8Du
// NEG_SLOPE = 0.2 hardcoded below.

#define ALOAD(p)     __hip_atomic_load((p),  __ATOMIC_RELAXED, __HIP_MEMORY_SCOPE_AGENT)
#define ASTORE(p, v) __hip_atomic_store((p), (v), __ATOMIC_RELAXED, __HIP_MEMORY_SCOPE_AGENT)

// order-preserving float <-> uint32 mapping
__device__ __forceinline__ unsigned int f2ord(float f) {
    unsigned int u = __float_as_uint(f);
    return (u & 0x80000000u) ? ~u : (u ^ 0x80000000u);
}
__device__ __forceinline__ float ord2f(unsigned int v) {
    unsigned int b = (v & 0x80000000u) ? (v ^ 0x80000000u) : ~v;
    return __uint_as_float(b);
}

// ---------------------------------------------------------------------------
// Fence-free per-batch barrier (64 blocks). Flags: agent-scope relaxed
// atomics ONLY (they mutate mid-kernel; plain loads could spin on a stale L1
// line). Publisher ordering: __syncthreads drains each wave's vmem (vmcnt(0))
// before the flag store, so prior agent-stores are LLC-visible first
// (validated R6/R7/R8). Deadlock-safe: grid 256 = 256 CUs, 1 block/CU.
// ---------------------------------------------------------------------------
__device__ __forceinline__ void batch_barrier(unsigned* bflags, unsigned magic,
                                              int cid, int tid, int wave, int lane) {
    __syncthreads();
    if (tid == 0) ASTORE(bflags + cid, magic);
    if (wave == 0) {
        for (;;) {
            unsigned a = ALOAD(bflags + lane);
            if (__all(a == magic)) break;
            __builtin_amdgcn_s_sleep(2);
        }
    }
    __syncthreads();
    asm volatile("" ::: "memory");
}

// ---------------------------------------------------------------------------
// Single fused kernel. grid 256 x 1024, 1 block/CU.
// Cross-phase data: PUBLISH via agent-scope atomic stores (write-through to
// LLC - proven by R8 passing with LLC-served readers). CONSUME via PLAIN WIDE
// vector loads: safe because (a) each array's first in-kernel read is strictly
// after the barrier that follows its writes -> no stale line can exist in the
// reader's L1/L2 (caches start dispatch-invalidated, proven by R4's
// cross-kernel plain-load coherence); (b) a local-L2 miss is served by LLC
// which holds the fresh agent-stored data. This replaces R8's ~2M narrow 8B
// ALOAD round-trips with 16B dwordx4 loads (~4x fewer LLC transactions).
// Phase A (bid = b*64+chunk): k/q dots for own 64 rows -> qkey, kks(LDS).
// Phase B: stage batch's qkey -> LDS, rank-count own 64 rows + fused boundary
//   count p_i = #{j: q_j < -k_i}; publish skey (sorted) + kp (orig order).
// Phase C (f = XCD-swizzled chunk): suffix/prefix scans of e^d*x_f,
//   e^{0.2d}*x_f (+denoms) over sorted rows in LDS; combine at p_i.
// LDS union: B: qs u64[4096]@0 | pc@32768 | pc2@34816 | kks@36864 (37.1K)
//            C: SUF1@0 PRE2@16416 SUFD@32832 PRED@49248 | wt/wb@65664 |
//               QmaxS@66176 (66.2K)
// ---------------------------------------------------------------------------
__global__ __launch_bounds__(1024) void fused_gat(
        const float* __restrict__ x, const float* __restrict__ wk,
        const float* __restrict__ wq, unsigned* __restrict__ flags1,
        unsigned* __restrict__ flags2,
        unsigned long long* __restrict__ qkey,
        unsigned long long* __restrict__ skey,
        unsigned long long* __restrict__ kp,
        float* __restrict__ out) {
    __shared__ __align__(16) char smem[66432];
    const int bid = blockIdx.x;
    const int tid = threadIdx.x;
    const int wave = tid >> 6, lane = tid & 63;
    const int b = bid >> 6, chunk = bid & 63;
    unsigned* bf1 = flags1 + (b << 6);
    unsigned* bf2 = flags2 + (b << 6);

    float* kks = (float*)(smem + 36864);     // [64] own-chunk k dots (A -> B)

    // flag2 hygiene (for replay without re-poison): ordered before flag1 by
    // program order + vmcnt drain; barrier-1 gates all flags2 polls.
    if (tid == 0) ASTORE(bf2 + chunk, 0u);

    // ---- Phase A: dots for own chunk (16 lanes per row) -------------------
    {
        const int row = tid >> 4;            // local row 0..63
        const int fq = tid & 15;
        const int grow = (chunk << 6) + row;
        const int f0 = fq << 2;
        float4 xv = *(const float4*)(x + ((size_t)b * N + grow) * F + f0);
        float4 k4 = *(const float4*)(wk + f0);
        float4 q4 = *(const float4*)(wq + f0);
        float kk = xv.x * k4.x + xv.y * k4.y + xv.z * k4.z + xv.w * k4.w;
        float qq = xv.x * q4.x + xv.y * q4.y + xv.z * q4.z + xv.w * q4.w;
#pragma unroll
        for (int off = 1; off <= 8; off <<= 1) {
            kk += __shfl_xor(kk, off, 16);
            qq += __shfl_xor(qq, off, 16);
        }
        if (fq == 0) {
            kks[row] = kk;
            ASTORE(qkey + b * N + grow,
                   ((unsigned long long)f2ord(qq) << 32) | (unsigned int)grow);
        }
    }
    batch_barrier(bf1, MAGIC1, chunk, tid, wave, lane);

    // ---- Phase B: rank + boundary count -----------------------------------
    {
        unsigned long long* qs = (unsigned long long*)smem;          // 32 KB
        unsigned short (*pc)[64] = (unsigned short(*)[64])(smem + 32768);
        unsigned short (*pc2)[64] = (unsigned short(*)[64])(smem + 34816);
        // plain wide staging: first in-kernel read of qkey, post-barrier ->
        // no stale lines possible; L2 miss served fresh from LLC.
        const ulonglong2* qb2 = (const ulonglong2*)(qkey + b * N);
        ulonglong2* qs2 = (ulonglong2*)qs;
        qs2[tid] = qb2[tid];
        qs2[tid + 1024] = qb2[tid + 1024];
        const float kk = kks[lane];
        const unsigned int thetaOrd = f2ord(-kk);
        __syncthreads();

        const unsigned long long myKey = qs[(chunk << 6) + lane];
        int cnt = 0, cnt2 = 0;
        const ulonglong2* q2 = (const ulonglong2*)qs;
        const int s0 = wave * 128;            // ulonglong2 units
#pragma unroll 8
        for (int t2 = 0; t2 < 128; ++t2) {
            ulonglong2 v = q2[s0 + t2];       // wave-uniform broadcast read
            cnt  += (int)(v.x < myKey) + (int)(v.y < myKey);
            cnt2 += (int)((unsigned int)(v.x >> 32) < thetaOrd)
                  + (int)((unsigned int)(v.y >> 32) < thetaOrd);
        }
        pc[wave][lane]  = (unsigned short)cnt;
        pc2[wave][lane] = (unsigned short)cnt2;
        __syncthreads();

        if (wave == 0) {
            int r = 0, p = 0;
#pragma unroll
            for (int w = 0; w < 16; ++w) { r += pc[w][lane]; p += pc2[w][lane]; }
            ASTORE(skey + b * N + r, myKey);
            ASTORE(kp + b * N + (chunk << 6) + lane,
                   ((unsigned long long)__float_as_uint(kk) << 32)
                 | (unsigned int)p);
        }
    }
    batch_barrier(bf2, MAGIC2, chunk, tid, wave, lane);

    // ---- Phase C: scans + combine (f = swizzled chunk) --------------------
    {
        const int f = ((chunk & 7) << 3) | (chunk >> 3);   // XCD locality
        float* SUF1 = (float*)smem;
        float* PRE2 = (float*)(smem + 16416);
        float* SUFD = (float*)(smem + 32832);
        float* PRED = (float*)(smem + 49248);
        float* wt1  = (float*)(smem + 65664);
        float* wtd1 = (float*)(smem + 65728);
        float* wt2  = (float*)(smem + 65792);
        float* wtd2 = (float*)(smem + 65856);
        float* wb1  = (float*)(smem + 65920);
        float* wbd1 = (float*)(smem + 65984);
        float* wb2  = (float*)(smem + 66048);
        float* wbd2 = (float*)(smem + 66112);
        float* QmaxS = (float*)(smem + 66176);
        const int t0 = tid << 2;

        if (tid == 0)
            QmaxS[0] = ord2f((unsigned int)(skey[b * N + N - 1] >> 32));
        __syncthreads();
        const float Qmax = QmaxS[0];

        // plain wide loads (first touch post-barrier -> fresh, see header)
        ulonglong2 s01 = *(const ulonglong2*)(skey + b * N + t0);
        ulonglong2 s23 = *(const ulonglong2*)(skey + b * N + t0 + 2);
        ulonglong2 k01 = *(const ulonglong2*)(kp + b * N + t0);
        ulonglong2 k23 = *(const ulonglong2*)(kp + b * N + t0 + 2);
        unsigned long long sk[4] = {s01.x, s01.y, s23.x, s23.y};
        unsigned long long kv[4] = {k01.x, k01.y, k23.x, k23.y};
        float e1[4], e2[4], w1[4], w2[4];
        const float* xbf = x + (size_t)b * N * F + f;
#pragma unroll
        for (int r = 0; r < 4; ++r) {
            float qv = ord2f((unsigned int)(sk[r] >> 32));
            unsigned ia = (unsigned int)sk[r] & (N - 1);   // fault guard
            float d = qv - Qmax;
            e1[r] = __expf(d);
            e2[r] = __expf(0.2f * d);
            float xf = xbf[(size_t)ia * F];   // plain load, L2-resident
            w1[r] = e1[r] * xf;
            w2[r] = e2[r] * xf;
        }

        // thread-local: exclusive prefix (w2,e2), inclusive suffix (w1,e1)
        float lp2_0 = 0.f, lp2_1 = w2[0], lp2_2 = lp2_1 + w2[1], lp2_3 = lp2_2 + w2[2];
        float T2 = lp2_3 + w2[3];
        float lpd_0 = 0.f, lpd_1 = e2[0], lpd_2 = lpd_1 + e2[1], lpd_3 = lpd_2 + e2[2];
        float TD2 = lpd_3 + e2[3];
        float ls1_3 = w1[3], ls1_2 = w1[2] + ls1_3, ls1_1 = w1[1] + ls1_2, ls1_0 = w1[0] + ls1_1;
        float T1 = ls1_0;
        float lsd_3 = e1[3], lsd_2 = e1[2] + lsd_3, lsd_1 = e1[1] + lsd_2, lsd_0 = e1[0] + lsd_1;
        float TD1 = lsd_0;

        // wave-level inclusive prefix (up) and inclusive suffix (down)
        float ip2 = T2, ipd2 = TD2;
#pragma unroll
        for (int d = 1; d < 64; d <<= 1) {
            float n1 = __shfl_up(ip2, d, 64);
            float n2 = __shfl_up(ipd2, d, 64);
            if (lane >= d) { ip2 += n1; ipd2 += n2; }
        }
        float is1 = T1, isd1 = TD1;
#pragma unroll
        for (int d = 1; d < 64; d <<= 1) {
            float n1 = __shfl_down(is1, d, 64);
            float n2 = __shfl_down(isd1, d, 64);
            if (lane + d < 64) { is1 += n1; isd1 += n2; }
        }
        if (lane == 63) { wt2[wave] = ip2; wtd2[wave] = ipd2; }
        if (lane == 0)  { wt1[wave] = is1; wtd1[wave] = isd1; }
        __syncthreads();
        // wave-base scans, 16-lane-parallel
        if (wave == 0 && lane < 16) {
            float v = wt2[lane], vd = wtd2[lane];
            float s = v, sd = vd;
#pragma unroll
            for (int d = 1; d < 16; d <<= 1) {
                float n1 = __shfl_up(s, d, 64);
                float n2 = __shfl_up(sd, d, 64);
                if (lane >= d) { s += n1; sd += n2; }
            }
            wb2[lane] = s - v; wbd2[lane] = sd - vd;
            if (lane == 15) { PRE2[N] = s; PRED[N] = sd; }
        }
        if (wave == 1 && lane < 16) {
            float v = wt1[lane], vd = wtd1[lane];
            float s = v, sd = vd;
#pragma unroll
            for (int d = 1; d < 16; d <<= 1) {
                float n1 = __shfl_down(s, d, 64);
                float n2 = __shfl_down(sd, d, 64);
                if (lane + d < 16) { s += n1; sd += n2; }
            }
            wb1[lane] = s - v; wbd1[lane] = sd - vd;
            if (lane == 0) { SUF1[N] = 0.f; SUFD[N] = 0.f; }
        }
        __syncthreads();
        float bp2 = wb2[wave] + (ip2 - T2);        // exclusive prefix base
        float bpd = wbd2[wave] + (ipd2 - TD2);
        float bs1 = wb1[wave] + (is1 - T1);        // suffix base (strictly after)
        float bsd = wbd1[wave] + (isd1 - TD1);
        float4 o;
        o.x = bp2 + lp2_0; o.y = bp2 + lp2_1; o.z = bp2 + lp2_2; o.w = bp2 + lp2_3;
        *(float4*)(PRE2 + t0) = o;
        o.x = bpd + lpd_0; o.y = bpd + lpd_1; o.z = bpd + lpd_2; o.w = bpd + lpd_3;
        *(float4*)(PRED + t0) = o;
        o.x = bs1 + ls1_0; o.y = bs1 + ls1_1; o.z = bs1 + ls1_2; o.w = bs1 + ls1_3;
        *(float4*)(SUF1 + t0) = o;
        o.x = bsd + lsd_0; o.y = bsd + lsd_1; o.z = bsd + lsd_2; o.w = bsd + lsd_3;
        *(float4*)(SUFD + t0) = o;
        __syncthreads();

        // lookup: 4 original rows per thread (kk, p packed in kp)
        float ra[4];
#pragma unroll
        for (int r = 0; r < 4; ++r) {
            float kk = __uint_as_float((unsigned int)(kv[r] >> 32));
            int p = (int)(kv[r] & 0xFFFFFFFFu);
            if ((unsigned)p > N) p = N;            // garbage guard
            float u = kk + Qmax;
            float M = fmaxf(u, 0.2f * u);
            float c1 = __expf(u - M);
            float c2 = __expf(0.2f * u - M);
            float num = c1 * SUF1[p] + c2 * PRE2[p];
            float den = c1 * SUFD[p] + c2 * PRED[p];
            ra[r] = num / den;
        }
        float4 res; res.x = ra[0]; res.y = ra[1]; res.z = ra[2]; res.w = ra[3];
        *(float4*)(out + ((size_t)(b * F + f)) * N + t0) = res;
    }

    // flag1 hygiene: safe, all batch blocks passed barrier-1 long before here.
    if (tid == 0) ASTORE(bf1 + chunk, 0u);
}

// ---------------------------------------------------------------------------
extern "C" void kernel_launch(void* const* d_in, const int* in_sizes, int n_in,
                              void* d_out, int out_size, void* d_ws, size_t ws_size,
                              hipStream_t stream) {
    const float* x  = (const float*)d_in[0];
    const float* wk = (const float*)d_in[1];
    const float* wq = (const float*)d_in[2];
    float* out = (float*)d_out;

    // ws layout (floats): flags1[256](u32) flags2[256](u32) |
    //   qkey(u64)[BZ*N] | skey(u64)[BZ*N] | kp(u64)[BZ*N]
    float* wsf = (float*)d_ws;
    unsigned* flags1 = (unsigned*)wsf;
    unsigned* flags2 = flags1 + 256;
    unsigned long long* qkey = (unsigned long long*)(wsf + 512);
    unsigned long long* skey = qkey + BZ * N;
    unsigned long long* kp   = skey + BZ * N;

    fused_gat<<<BZ * 64, 1024, 0, stream>>>(x, wk, wq, flags1, flags2,
                                            qkey, skey, kp, out);
}

// Round 10
// 79.717 us; speedup vs baseline: 1.2596x; 1.0234x over previous
//
#include <hip/hip_runtime.h>

#define N 4096
#define F 64
#define BZ 4
#define MAGIC1 0x1F2E3D4Cu
#define MAGIC2 0x5A6B7C8Du
// NEG_SLOPE = 0.2 hardcoded below.

#define ALOAD(p)     __hip_atomic_load((p),  __ATOMIC_RELAXED, __HIP_MEMORY_SCOPE_AGENT)
#define ASTORE(p, v) __hip_atomic_store((p), (v), __ATOMIC_RELAXED, __HIP_MEMORY_SCOPE_AGENT)

// order-preserving float <-> uint32 mapping
__device__ __forceinline__ unsigned int f2ord(float f) {
    unsigned int u = __float_as_uint(f);
    return (u & 0x80000000u) ? ~u : (u ^ 0x80000000u);
}
__device__ __forceinline__ float ord2f(unsigned int v) {
    unsigned int b = (v & 0x80000000u) ? (v ^ 0x80000000u) : ~v;
    return __uint_as_float(b);
}

// ---------------------------------------------------------------------------
// Leader-aggregated fence-free per-batch barrier. R9's poll had 64 blocks x
// 64 lanes = 4096 atomic loads/round hammering 4 LLC lines -> the lines
// saturate and the WRITERS' flag stores queue behind reader loads (same
// contention mechanism R7->R8 proved: cutting poll traffic 16x saved 12us).
// Here: each block stores its arrival flag once; ONLY the leader (chunk 0)
// polls the 64 flags (one wave, 64 loads/round); leader then sets a single
// done flag; 63 blocks poll THAT with a single lane (1 load/block/round).
// ~127 transactions/round vs 4096. Flags padded to distinct lines per batch.
// Ordering: __syncthreads drains vmem (vmcnt(0)) before the flag store, so
// prior agent-stores are LLC-visible first (validated R6-R9). Poison-safe:
// MAGIC != fill poison; fill re-poisons ws every iteration (verified).
// Deadlock-safe: grid 256 = 256 CUs, 1 block/CU, all resident.
// ---------------------------------------------------------------------------
__device__ __forceinline__ void batch_barrier(unsigned* bflags, unsigned* bdone,
                                              unsigned magic, int chunk,
                                              int tid, int wave, int lane) {
    __syncthreads();
    if (tid == 0) ASTORE(bflags + chunk, magic);
    if (chunk == 0) {
        if (wave == 0) {
            for (;;) {
                unsigned a = ALOAD(bflags + lane);
                if (__all(a == magic)) break;
                __builtin_amdgcn_s_sleep(2);
            }
            if (lane == 0) ASTORE(bdone, magic);
        }
    } else {
        if (wave == 0 && lane == 0) {
            while (ALOAD(bdone) != magic) __builtin_amdgcn_s_sleep(2);
        }
    }
    __syncthreads();
    asm volatile("" ::: "memory");
}

// ---------------------------------------------------------------------------
// Single fused kernel. grid 256 x 1024, 1 block/CU. (Structure = passing R9.)
// Cross-phase data: publish via agent-scope atomic stores (write-through to
// LLC); consume via PLAIN WIDE vector loads - safe because each array's first
// in-kernel read is strictly post-barrier (no stale line can exist; caches
// start dispatch-invalidated; LLC serves fresh data). Validated R9.
// Phase A (bid = b*64+chunk): k/q dots for own 64 rows -> qkey, kks(LDS).
// Phase B: stage batch's qkey -> LDS, rank-count own 64 rows + fused boundary
//   count p_i = #{j: q_j < -k_i}; publish skey (sorted) + kp (orig order).
// Phase C (f = XCD-swizzled chunk): suffix/prefix scans of e^d*x_f,
//   e^{0.2d}*x_f (+denoms) over sorted rows in LDS; combine at p_i.
// LDS union: B: qs u64[4096]@0 | pc@32768 | pc2@34816 | kks@36864 (37.1K)
//            C: SUF1@0 PRE2@16416 SUFD@32832 PRED@49248 | wt/wb@65664 |
//               QmaxS@66176 (66.2K)
// ---------------------------------------------------------------------------
__global__ __launch_bounds__(1024) void fused_gat(
        const float* __restrict__ x, const float* __restrict__ wk,
        const float* __restrict__ wq, unsigned* __restrict__ flags1,
        unsigned* __restrict__ flags2, unsigned* __restrict__ done1,
        unsigned* __restrict__ done2,
        unsigned long long* __restrict__ qkey,
        unsigned long long* __restrict__ skey,
        unsigned long long* __restrict__ kp,
        float* __restrict__ out) {
    __shared__ __align__(16) char smem[66432];
    const int bid = blockIdx.x;
    const int tid = threadIdx.x;
    const int wave = tid >> 6, lane = tid & 63;
    const int b = bid >> 6, chunk = bid & 63;
    unsigned* bf1 = flags1 + (b << 8);       // 256-u32 (1 KB) stride per batch
    unsigned* bf2 = flags2 + (b << 8);
    unsigned* bd1 = done1 + (b << 6);        // 64-u32 (256 B) stride per batch
    unsigned* bd2 = done2 + (b << 6);

    float* kks = (float*)(smem + 36864);     // [64] own-chunk k dots (A -> B)

    // ---- Phase A: dots for own chunk (16 lanes per row) -------------------
    {
        const int row = tid >> 4;            // local row 0..63
        const int fq = tid & 15;
        const int grow = (chunk << 6) + row;
        const int f0 = fq << 2;
        float4 xv = *(const float4*)(x + ((size_t)b * N + grow) * F + f0);
        float4 k4 = *(const float4*)(wk + f0);
        float4 q4 = *(const float4*)(wq + f0);
        float kk = xv.x * k4.x + xv.y * k4.y + xv.z * k4.z + xv.w * k4.w;
        float qq = xv.x * q4.x + xv.y * q4.y + xv.z * q4.z + xv.w * q4.w;
#pragma unroll
        for (int off = 1; off <= 8; off <<= 1) {
            kk += __shfl_xor(kk, off, 16);
            qq += __shfl_xor(qq, off, 16);
        }
        if (fq == 0) {
            kks[row] = kk;
            ASTORE(qkey + b * N + grow,
                   ((unsigned long long)f2ord(qq) << 32) | (unsigned int)grow);
        }
    }
    batch_barrier(bf1, bd1, MAGIC1, chunk, tid, wave, lane);

    // ---- Phase B: rank + boundary count -----------------------------------
    {
        unsigned long long* qs = (unsigned long long*)smem;          // 32 KB
        unsigned short (*pc)[64] = (unsigned short(*)[64])(smem + 32768);
        unsigned short (*pc2)[64] = (unsigned short(*)[64])(smem + 34816);
        // plain wide staging: first in-kernel read of qkey, post-barrier ->
        // no stale lines possible; local-L2 miss served fresh from LLC.
        const ulonglong2* qb2 = (const ulonglong2*)(qkey + b * N);
        ulonglong2* qs2 = (ulonglong2*)qs;
        qs2[tid] = qb2[tid];
        qs2[tid + 1024] = qb2[tid + 1024];
        const float kk = kks[lane];
        const unsigned int thetaOrd = f2ord(-kk);
        __syncthreads();

        const unsigned long long myKey = qs[(chunk << 6) + lane];
        int cnt = 0, cnt2 = 0;
        const ulonglong2* q2 = (const ulonglong2*)qs;
        const int s0 = wave * 128;            // ulonglong2 units
#pragma unroll 8
        for (int t2 = 0; t2 < 128; ++t2) {
            ulonglong2 v = q2[s0 + t2];       // wave-uniform broadcast read
            cnt  += (int)(v.x < myKey) + (int)(v.y < myKey);
            cnt2 += (int)((unsigned int)(v.x >> 32) < thetaOrd)
                  + (int)((unsigned int)(v.y >> 32) < thetaOrd);
        }
        pc[wave][lane]  = (unsigned short)cnt;
        pc2[wave][lane] = (unsigned short)cnt2;
        __syncthreads();

        if (wave == 0) {
            int r = 0, p = 0;
#pragma unroll
            for (int w = 0; w < 16; ++w) { r += pc[w][lane]; p += pc2[w][lane]; }
            ASTORE(skey + b * N + r, myKey);
            ASTORE(kp + b * N + (chunk << 6) + lane,
                   ((unsigned long long)__float_as_uint(kk) << 32)
                 | (unsigned int)p);
        }
    }
    batch_barrier(bf2, bd2, MAGIC2, chunk, tid, wave, lane);

    // ---- Phase C: scans + combine (f = swizzled chunk) --------------------
    {
        const int f = ((chunk & 7) << 3) | (chunk >> 3);   // XCD locality
        float* SUF1 = (float*)smem;
        float* PRE2 = (float*)(smem + 16416);
        float* SUFD = (float*)(smem + 32832);
        float* PRED = (float*)(smem + 49248);
        float* wt1  = (float*)(smem + 65664);
        float* wtd1 = (float*)(smem + 65728);
        float* wt2  = (float*)(smem + 65792);
        float* wtd2 = (float*)(smem + 65856);
        float* wb1  = (float*)(smem + 65920);
        float* wbd1 = (float*)(smem + 65984);
        float* wb2  = (float*)(smem + 66048);
        float* wbd2 = (float*)(smem + 66112);
        float* QmaxS = (float*)(smem + 66176);
        const int t0 = tid << 2;

        if (tid == 0)
            QmaxS[0] = ord2f((unsigned int)(skey[b * N + N - 1] >> 32));
        __syncthreads();
        const float Qmax = QmaxS[0];

        // plain wide loads (first touch post-barrier -> fresh, validated R9)
        ulonglong2 s01 = *(const ulonglong2*)(skey + b * N + t0);
        ulonglong2 s23 = *(const ulonglong2*)(skey + b * N + t0 + 2);
        ulonglong2 k01 = *(const ulonglong2*)(kp + b * N + t0);
        ulonglong2 k23 = *(const ulonglong2*)(kp + b * N + t0 + 2);
        unsigned long long sk[4] = {s01.x, s01.y, s23.x, s23.y};
        unsigned long long kv[4] = {k01.x, k01.y, k23.x, k23.y};
        float e1[4], e2[4], w1[4], w2[4];
        const float* xbf = x + (size_t)b * N * F + f;
#pragma unroll
        for (int r = 0; r < 4; ++r) {
            float qv = ord2f((unsigned int)(sk[r] >> 32));
            unsigned ia = (unsigned int)sk[r] & (N - 1);   // fault guard
            float d = qv - Qmax;
            e1[r] = __expf(d);
            e2[r] = __expf(0.2f * d);
            float xf = xbf[(size_t)ia * F];   // plain load, L2-resident
            w1[r] = e1[r] * xf;
            w2[r] = e2[r] * xf;
        }

        // thread-local: exclusive prefix (w2,e2), inclusive suffix (w1,e1)
        float lp2_0 = 0.f, lp2_1 = w2[0], lp2_2 = lp2_1 + w2[1], lp2_3 = lp2_2 + w2[2];
        float T2 = lp2_3 + w2[3];
        float lpd_0 = 0.f, lpd_1 = e2[0], lpd_2 = lpd_1 + e2[1], lpd_3 = lpd_2 + e2[2];
        float TD2 = lpd_3 + e2[3];
        float ls1_3 = w1[3], ls1_2 = w1[2] + ls1_3, ls1_1 = w1[1] + ls1_2, ls1_0 = w1[0] + ls1_1;
        float T1 = ls1_0;
        float lsd_3 = e1[3], lsd_2 = e1[2] + lsd_3, lsd_1 = e1[1] + lsd_2, lsd_0 = e1[0] + lsd_1;
        float TD1 = lsd_0;

        // wave-level inclusive prefix (up) and inclusive suffix (down)
        float ip2 = T2, ipd2 = TD2;
#pragma unroll
        for (int d = 1; d < 64; d <<= 1) {
            float n1 = __shfl_up(ip2, d, 64);
            float n2 = __shfl_up(ipd2, d, 64);
            if (lane >= d) { ip2 += n1; ipd2 += n2; }
        }
        float is1 = T1, isd1 = TD1;
#pragma unroll
        for (int d = 1; d < 64; d <<= 1) {
            float n1 = __shfl_down(is1, d, 64);
            float n2 = __shfl_down(isd1, d, 64);
            if (lane + d < 64) { is1 += n1; isd1 += n2; }
        }
        if (lane == 63) { wt2[wave] = ip2; wtd2[wave] = ipd2; }
        if (lane == 0)  { wt1[wave] = is1; wtd1[wave] = isd1; }
        __syncthreads();
        // wave-base scans, 16-lane-parallel
        if (wave == 0 && lane < 16) {
            float v = wt2[lane], vd = wtd2[lane];
            float s = v, sd = vd;
#pragma unroll
            for (int d = 1; d < 16; d <<= 1) {
                float n1 = __shfl_up(s, d, 64);
                float n2 = __shfl_up(sd, d, 64);
                if (lane >= d) { s += n1; sd += n2; }
            }
            wb2[lane] = s - v; wbd2[lane] = sd - vd;
            if (lane == 15) { PRE2[N] = s; PRED[N] = sd; }
        }
        if (wave == 1 && lane < 16) {
            float v = wt1[lane], vd = wtd1[lane];
            float s = v, sd = vd;
#pragma unroll
            for (int d = 1; d < 16; d <<= 1) {
                float n1 = __shfl_down(s, d, 64);
                float n2 = __shfl_down(sd, d, 64);
                if (lane + d < 16) { s += n1; sd += n2; }
            }
            wb1[lane] = s - v; wbd1[lane] = sd - vd;
            if (lane == 0) { SUF1[N] = 0.f; SUFD[N] = 0.f; }
        }
        __syncthreads();
        float bp2 = wb2[wave] + (ip2 - T2);        // exclusive prefix base
        float bpd = wbd2[wave] + (ipd2 - TD2);
        float bs1 = wb1[wave] + (is1 - T1);        // suffix base (strictly after)
        float bsd = wbd1[wave] + (isd1 - TD1);
        float4 o;
        o.x = bp2 + lp2_0; o.y = bp2 + lp2_1; o.z = bp2 + lp2_2; o.w = bp2 + lp2_3;
        *(float4*)(PRE2 + t0) = o;
        o.x = bpd + lpd_0; o.y = bpd + lpd_1; o.z = bpd + lpd_2; o.w = bpd + lpd_3;
        *(float4*)(PRED + t0) = o;
        o.x = bs1 + ls1_0; o.y = bs1 + ls1_1; o.z = bs1 + ls1_2; o.w = bs1 + ls1_3;
        *(float4*)(SUF1 + t0) = o;
        o.x = bsd + lsd_0; o.y = bsd + lsd_1; o.z = bsd + lsd_2; o.w = bsd + lsd_3;
        *(float4*)(SUFD + t0) = o;
        __syncthreads();

        // lookup: 4 original rows per thread (kk, p packed in kp)
        float ra[4];
#pragma unroll
        for (int r = 0; r < 4; ++r) {
            float kk = __uint_as_float((unsigned int)(kv[r] >> 32));
            int p = (int)(kv[r] & 0xFFFFFFFFu);
            if ((unsigned)p > N) p = N;            // garbage guard
            float u = kk + Qmax;
            float M = fmaxf(u, 0.2f * u);
            float c1 = __expf(u - M);
            float c2 = __expf(0.2f * u - M);
            float num = c1 * SUF1[p] + c2 * PRE2[p];
            float den = c1 * SUFD[p] + c2 * PRED[p];
            ra[r] = num / den;
        }
        float4 res; res.x = ra[0]; res.y = ra[1]; res.z = ra[2]; res.w = ra[3];
        *(float4*)(out + ((size_t)(b * F + f)) * N + t0) = res;
    }
}

// ---------------------------------------------------------------------------
extern "C" void kernel_launch(void* const* d_in, const int* in_sizes, int n_in,
                              void* d_out, int out_size, void* d_ws, size_t ws_size,
                              hipStream_t stream) {
    const float* x  = (const float*)d_in[0];
    const float* wk = (const float*)d_in[1];
    const float* wq = (const float*)d_in[2];
    float* out = (float*)d_out;

    // ws layout (u32 units): flags1[4*256] | flags2[4*256] | done1[4*64] |
    //   done2[4*64] | then u64 arrays: qkey[BZ*N] | skey[BZ*N] | kp[BZ*N]
    unsigned* wsu = (unsigned*)d_ws;
    unsigned* flags1 = wsu;
    unsigned* flags2 = flags1 + 4 * 256;
    unsigned* done1  = flags2 + 4 * 256;
    unsigned* done2  = done1 + 4 * 64;
    unsigned long long* qkey = (unsigned long long*)(done2 + 4 * 64 + 64);
    unsigned long long* skey = qkey + BZ * N;
    unsigned long long* kp   = skey + BZ * N;

    fused_gat<<<BZ * 64, 1024, 0, stream>>>(x, wk, wq, flags1, flags2,
                                            done1, done2, qkey, skey, kp, out);
}

// Round 11
// 79.192 us; speedup vs baseline: 1.2679x; 1.0066x over previous
//
#include <hip/hip_runtime.h>

#define N 4096
#define F 64
#define BZ 4
#define MAGIC1 0x1F2E3D4Cu
#define MAGIC2 0x5A6B7C8Du
// NEG_SLOPE = 0.2 hardcoded below.

#define ALOAD(p)     __hip_atomic_load((p),  __ATOMIC_RELAXED, __HIP_MEMORY_SCOPE_AGENT)
#define ASTORE(p, v) __hip_atomic_store((p), (v), __ATOMIC_RELAXED, __HIP_MEMORY_SCOPE_AGENT)

// order-preserving float <-> uint32 mapping
__device__ __forceinline__ unsigned int f2ord(float f) {
    unsigned int u = __float_as_uint(f);
    return (u & 0x80000000u) ? ~u : (u ^ 0x80000000u);
}
__device__ __forceinline__ float ord2f(unsigned int v) {
    unsigned int b = (v & 0x80000000u) ? (v ^ 0x80000000u) : ~v;
    return __uint_as_float(b);
}
__device__ __forceinline__ unsigned umax2(unsigned a, unsigned b) {
    return a > b ? a : b;
}

// ---------------------------------------------------------------------------
// Leader-aggregated fence-free per-batch barrier (validated R10): each block
// stores its arrival flag; leader (chunk 0) polls the 64 flags with one wave;
// leader sets a single done flag; others poll that with one lane. Cross-phase
// data moves via agent-scope atomic stores (LLC write-through) and is consumed
// by plain wide loads (first touch strictly post-barrier -> no stale lines;
// validated R9/R10). Deadlock-safe: grid 256 = 256 CUs, 1 block/CU.
// ---------------------------------------------------------------------------
__device__ __forceinline__ void batch_barrier(unsigned* bflags, unsigned* bdone,
                                              unsigned magic, int chunk,
                                              int tid, int wave, int lane) {
    __syncthreads();
    if (tid == 0) ASTORE(bflags + chunk, magic);
    if (chunk == 0) {
        if (wave == 0) {
            for (;;) {
                unsigned a = ALOAD(bflags + lane);
                if (__all(a == magic)) break;
                __builtin_amdgcn_s_sleep(2);
            }
            if (lane == 0) ASTORE(bdone, magic);
        }
    } else {
        if (wave == 0 && lane == 0) {
            while (ALOAD(bdone) != magic) __builtin_amdgcn_s_sleep(2);
        }
    }
    __syncthreads();
    asm volatile("" ::: "memory");
}

// ---------------------------------------------------------------------------
// Single fused kernel. grid 256 x 1024, 1 block/CU.
// Phase A (bid=b*64+chunk): k/q dots own 64 rows -> karr, qkey, kks(LDS).
// Phase B: stage batch's qkey -> LDS qs (+ Qmax max-reduce during staging),
//   rank-count own 64 rows + boundary count p_i = #{j: q_j < -k_i};
//   publish ONE u32/row: pr = (p<<16) | rank.
// Barrier 2 is inlined with OVERLAP: after the arrival store, each thread
//   does all barrier-independent Phase-C input work (x loads in ORIGINAL row
//   order, q from LDS qs, karr wide load, all 16 exps) inside the wait
//   shadow; only the rank/p array crosses the barrier.
// Phase C post-barrier: scatter e1*x/e2*x/e1/e2 by rank into the scan arrays
//   (permutation -> no collisions), read back own sorted positions, then the
//   exact R10 scans + lookup. Summation order identical to R10.
// LDS union: B: qs u64[4096]@0 | pc@32768 | pc2@34816 | kks@36864 |
//               wmax@37120 | QmaxS@37184 (37.2K)
//            C: SUF1@0 PRE2@16416 SUFD@32832 PRED@49248 | wt/wb@65664 (66.2K)
//   (kks/wmax/QmaxS/qs live inside Phase-C array space but are consumed into
//    registers pre-barrier; scatter happens only after the closing sync.)
// ---------------------------------------------------------------------------
__global__ __launch_bounds__(1024) void fused_gat(
        const float* __restrict__ x, const float* __restrict__ wk,
        const float* __restrict__ wq, unsigned* __restrict__ flags1,
        unsigned* __restrict__ flags2, unsigned* __restrict__ done1,
        unsigned* __restrict__ done2, float* __restrict__ karr,
        unsigned long long* __restrict__ qkey, unsigned* __restrict__ prA,
        float* __restrict__ out) {
    __shared__ __align__(16) char smem[66432];
    const int bid = blockIdx.x;
    const int tid = threadIdx.x;
    const int wave = tid >> 6, lane = tid & 63;
    const int b = bid >> 6, chunk = bid & 63;
    unsigned* bf1 = flags1 + (b << 8);       // 1 KB stride per batch
    unsigned* bf2 = flags2 + (b << 8);
    unsigned* bd1 = done1 + (b << 6);        // 256 B stride per batch
    unsigned* bd2 = done2 + (b << 6);

    unsigned long long* qs = (unsigned long long*)smem;              // 32 KB
    unsigned short (*pc)[64]  = (unsigned short(*)[64])(smem + 32768);
    unsigned short (*pc2)[64] = (unsigned short(*)[64])(smem + 34816);
    float* kks      = (float*)(smem + 36864);
    unsigned* wmaxU = (unsigned*)(smem + 37120);
    float* QmaxS    = (float*)(smem + 37184);

    // ---- Phase A: dots for own chunk (16 lanes per row) -------------------
    {
        const int row = tid >> 4;            // local row 0..63
        const int fq = tid & 15;
        const int grow = (chunk << 6) + row;
        const int f0 = fq << 2;
        float4 xv = *(const float4*)(x + ((size_t)b * N + grow) * F + f0);
        float4 k4 = *(const float4*)(wk + f0);
        float4 q4 = *(const float4*)(wq + f0);
        float kk = xv.x * k4.x + xv.y * k4.y + xv.z * k4.z + xv.w * k4.w;
        float qq = xv.x * q4.x + xv.y * q4.y + xv.z * q4.z + xv.w * q4.w;
#pragma unroll
        for (int off = 1; off <= 8; off <<= 1) {
            kk += __shfl_xor(kk, off, 16);
            qq += __shfl_xor(qq, off, 16);
        }
        if (fq == 0) {
            kks[row] = kk;
            ASTORE(karr + b * N + grow, kk);
            ASTORE(qkey + b * N + grow,
                   ((unsigned long long)f2ord(qq) << 32) | (unsigned int)grow);
        }
    }
    batch_barrier(bf1, bd1, MAGIC1, chunk, tid, wave, lane);

    // ---- Phase B: rank + boundary count + Qmax ----------------------------
    {
        const ulonglong2* qb2 = (const ulonglong2*)(qkey + b * N);
        ulonglong2* qs2 = (ulonglong2*)qs;
        ulonglong2 v0 = qb2[tid];
        ulonglong2 v1 = qb2[tid + 1024];
        qs2[tid] = v0;
        qs2[tid + 1024] = v1;
        unsigned mh = umax2(umax2((unsigned)(v0.x >> 32), (unsigned)(v0.y >> 32)),
                            umax2((unsigned)(v1.x >> 32), (unsigned)(v1.y >> 32)));
#pragma unroll
        for (int off = 1; off < 64; off <<= 1)
            mh = umax2(mh, (unsigned)__shfl_xor((int)mh, off, 64));
        if (lane == 0) wmaxU[wave] = mh;
        const float kk = kks[lane];
        const unsigned int thetaOrd = f2ord(-kk);
        __syncthreads();

        const unsigned long long myKey = qs[(chunk << 6) + lane];
        int cnt = 0, cnt2 = 0;
        const ulonglong2* q2 = (const ulonglong2*)qs;
        const int s0 = wave * 128;            // ulonglong2 units
#pragma unroll 8
        for (int t2 = 0; t2 < 128; ++t2) {
            ulonglong2 v = q2[s0 + t2];       // wave-uniform broadcast read
            cnt  += (int)(v.x < myKey) + (int)(v.y < myKey);
            cnt2 += (int)((unsigned int)(v.x >> 32) < thetaOrd)
                  + (int)((unsigned int)(v.y >> 32) < thetaOrd);
        }
        pc[wave][lane]  = (unsigned short)cnt;
        pc2[wave][lane] = (unsigned short)cnt2;
        __syncthreads();

        if (wave == 0) {
            int r = 0, p = 0;
#pragma unroll
            for (int w = 0; w < 16; ++w) { r += pc[w][lane]; p += pc2[w][lane]; }
            ASTORE(prA + b * N + (chunk << 6) + lane,
                   (((unsigned)p) << 16) | (unsigned)r);
            unsigned m2 = wmaxU[lane & 15];
#pragma unroll
            for (int off = 1; off < 16; off <<= 1)
                m2 = umax2(m2, (unsigned)__shfl_xor((int)m2, off, 16));
            if (lane == 0) QmaxS[0] = ord2f(m2);
        }
    }

    // ---- Barrier 2, inlined with overlap ----------------------------------
    __syncthreads();                          // drains publishes (vmcnt(0))
    if (tid == 0) ASTORE(bf2 + chunk, MAGIC2);

    // overlap work: all barrier-independent Phase-C input computation
    const int f = ((chunk & 7) << 3) | (chunk >> 3);   // XCD locality
    const int t0 = tid << 2;                  // own original rows t0..t0+3
    const float Qmax = QmaxS[0];
    const float* xp = x + ((size_t)b * N + t0) * F + f;
    float xf0 = xp[0], xf1 = xp[F], xf2 = xp[2 * F], xf3 = xp[3 * F];
    float4 kqv = *(const float4*)(karr + b * N + t0);  // post-bar1 first touch
    ulonglong2 qA = ((const ulonglong2*)qs)[t0 >> 1];
    ulonglong2 qB = ((const ulonglong2*)qs)[(t0 >> 1) + 1];
    float d0 = ord2f((unsigned)(qA.x >> 32)) - Qmax;
    float d1 = ord2f((unsigned)(qA.y >> 32)) - Qmax;
    float d2 = ord2f((unsigned)(qB.x >> 32)) - Qmax;
    float d3 = ord2f((unsigned)(qB.y >> 32)) - Qmax;
    float e1_0 = __expf(d0), e1_1 = __expf(d1), e1_2 = __expf(d2), e1_3 = __expf(d3);
    float e2_0 = __expf(0.2f * d0), e2_1 = __expf(0.2f * d1);
    float e2_2 = __expf(0.2f * d2), e2_3 = __expf(0.2f * d3);
    float w1_0 = e1_0 * xf0, w1_1 = e1_1 * xf1, w1_2 = e1_2 * xf2, w1_3 = e1_3 * xf3;
    float w2_0 = e2_0 * xf0, w2_1 = e2_1 * xf1, w2_2 = e2_2 * xf2, w2_3 = e2_3 * xf3;
    float u0 = kqv.x + Qmax, u1 = kqv.y + Qmax, u2 = kqv.z + Qmax, u3 = kqv.w + Qmax;
    float M0 = fmaxf(u0, 0.2f * u0), M1 = fmaxf(u1, 0.2f * u1);
    float M2 = fmaxf(u2, 0.2f * u2), M3 = fmaxf(u3, 0.2f * u3);
    float c1_0 = __expf(u0 - M0), c1_1 = __expf(u1 - M1);
    float c1_2 = __expf(u2 - M2), c1_3 = __expf(u3 - M3);
    float c2_0 = __expf(0.2f * u0 - M0), c2_1 = __expf(0.2f * u1 - M1);
    float c2_2 = __expf(0.2f * u2 - M2), c2_3 = __expf(0.2f * u3 - M3);

    // poll (leader-aggregated, as R10)
    if (chunk == 0) {
        if (wave == 0) {
            for (;;) {
                unsigned a = ALOAD(bf2 + lane);
                if (__all(a == MAGIC2)) break;
                __builtin_amdgcn_s_sleep(2);
            }
            if (lane == 0) ASTORE(bd2, MAGIC2);
        }
    } else {
        if (wave == 0 && lane == 0) {
            while (ALOAD(bd2) != MAGIC2) __builtin_amdgcn_s_sleep(2);
        }
    }
    __syncthreads();
    asm volatile("" ::: "memory");

    // ---- Phase C post-barrier: scatter -> scans -> lookup -----------------
    {
        float* SUF1 = (float*)smem;
        float* PRE2 = (float*)(smem + 16416);
        float* SUFD = (float*)(smem + 32832);
        float* PRED = (float*)(smem + 49248);
        float* wt1  = (float*)(smem + 65664);
        float* wtd1 = (float*)(smem + 65728);
        float* wt2  = (float*)(smem + 65792);
        float* wtd2 = (float*)(smem + 65856);
        float* wb1  = (float*)(smem + 65920);
        float* wbd1 = (float*)(smem + 65984);
        float* wb2  = (float*)(smem + 66048);
        float* wbd2 = (float*)(smem + 66112);

        // ranks + boundary counts (the ONLY post-barrier cross-block data)
        uint4 pv4 = *(const uint4*)(prA + b * N + t0);
        unsigned rk0 = pv4.x & 4095u, rk1 = pv4.y & 4095u;
        unsigned rk2 = pv4.z & 4095u, rk3 = pv4.w & 4095u;
        int p0 = (int)((pv4.x >> 16) & 0x1FFFu); if (p0 > N) p0 = N;
        int p1 = (int)((pv4.y >> 16) & 0x1FFFu); if (p1 > N) p1 = N;
        int p2 = (int)((pv4.z >> 16) & 0x1FFFu); if (p2 > N) p2 = N;
        int p3 = (int)((pv4.w >> 16) & 0x1FFFu); if (p3 > N) p3 = N;

        // scatter by rank (permutation -> unique positions)
        SUF1[rk0] = w1_0; SUF1[rk1] = w1_1; SUF1[rk2] = w1_2; SUF1[rk3] = w1_3;
        PRE2[rk0] = w2_0; PRE2[rk1] = w2_1; PRE2[rk2] = w2_2; PRE2[rk3] = w2_3;
        SUFD[rk0] = e1_0; SUFD[rk1] = e1_1; SUFD[rk2] = e1_2; SUFD[rk3] = e1_3;
        PRED[rk0] = e2_0; PRED[rk1] = e2_1; PRED[rk2] = e2_2; PRED[rk3] = e2_3;
        __syncthreads();

        // read back own sorted positions
        float4 rw1 = *(const float4*)(SUF1 + t0);
        float4 rw2 = *(const float4*)(PRE2 + t0);
        float4 re1 = *(const float4*)(SUFD + t0);
        float4 re2 = *(const float4*)(PRED + t0);

        // thread-local: exclusive prefix (rw2,re2), inclusive suffix (rw1,re1)
        float lp2_0 = 0.f, lp2_1 = rw2.x, lp2_2 = lp2_1 + rw2.y, lp2_3 = lp2_2 + rw2.z;
        float T2 = lp2_3 + rw2.w;
        float lpd_0 = 0.f, lpd_1 = re2.x, lpd_2 = lpd_1 + re2.y, lpd_3 = lpd_2 + re2.z;
        float TD2 = lpd_3 + re2.w;
        float ls1_3 = rw1.w, ls1_2 = rw1.z + ls1_3, ls1_1 = rw1.y + ls1_2, ls1_0 = rw1.x + ls1_1;
        float T1 = ls1_0;
        float lsd_3 = re1.w, lsd_2 = re1.z + lsd_3, lsd_1 = re1.y + lsd_2, lsd_0 = re1.x + lsd_1;
        float TD1 = lsd_0;

        // wave-level inclusive prefix (up) and inclusive suffix (down)
        float ip2 = T2, ipd2 = TD2;
#pragma unroll
        for (int d = 1; d < 64; d <<= 1) {
            float n1 = __shfl_up(ip2, d, 64);
            float n2 = __shfl_up(ipd2, d, 64);
            if (lane >= d) { ip2 += n1; ipd2 += n2; }
        }
        float is1 = T1, isd1 = TD1;
#pragma unroll
        for (int d = 1; d < 64; d <<= 1) {
            float n1 = __shfl_down(is1, d, 64);
            float n2 = __shfl_down(isd1, d, 64);
            if (lane + d < 64) { is1 += n1; isd1 += n2; }
        }
        if (lane == 63) { wt2[wave] = ip2; wtd2[wave] = ipd2; }
        if (lane == 0)  { wt1[wave] = is1; wtd1[wave] = isd1; }
        __syncthreads();
        // wave-base scans, 16-lane-parallel
        if (wave == 0 && lane < 16) {
            float v = wt2[lane], vd = wtd2[lane];
            float s = v, sd = vd;
#pragma unroll
            for (int d = 1; d < 16; d <<= 1) {
                float n1 = __shfl_up(s, d, 64);
                float n2 = __shfl_up(sd, d, 64);
                if (lane >= d) { s += n1; sd += n2; }
            }
            wb2[lane] = s - v; wbd2[lane] = sd - vd;
            if (lane == 15) { PRE2[N] = s; PRED[N] = sd; }
        }
        if (wave == 1 && lane < 16) {
            float v = wt1[lane], vd = wtd1[lane];
            float s = v, sd = vd;
#pragma unroll
            for (int d = 1; d < 16; d <<= 1) {
                float n1 = __shfl_down(s, d, 64);
                float n2 = __shfl_down(sd, d, 64);
                if (lane + d < 16) { s += n1; sd += n2; }
            }
            wb1[lane] = s - v; wbd1[lane] = sd - vd;
            if (lane == 0) { SUF1[N] = 0.f; SUFD[N] = 0.f; }
        }
        __syncthreads();
        float bp2 = wb2[wave] + (ip2 - T2);        // exclusive prefix base
        float bpd = wbd2[wave] + (ipd2 - TD2);
        float bs1 = wb1[wave] + (is1 - T1);        // suffix base (strictly after)
        float bsd = wbd1[wave] + (isd1 - TD1);
        float4 o;
        o.x = bp2 + lp2_0; o.y = bp2 + lp2_1; o.z = bp2 + lp2_2; o.w = bp2 + lp2_3;
        *(float4*)(PRE2 + t0) = o;
        o.x = bpd + lpd_0; o.y = bpd + lpd_1; o.z = bpd + lpd_2; o.w = bpd + lpd_3;
        *(float4*)(PRED + t0) = o;
        o.x = bs1 + ls1_0; o.y = bs1 + ls1_1; o.z = bs1 + ls1_2; o.w = bs1 + ls1_3;
        *(float4*)(SUF1 + t0) = o;
        o.x = bsd + lsd_0; o.y = bsd + lsd_1; o.z = bsd + lsd_2; o.w = bsd + lsd_3;
        *(float4*)(SUFD + t0) = o;
        __syncthreads();

        // lookup with precomputed c1/c2
        float4 res;
        res.x = (c1_0 * SUF1[p0] + c2_0 * PRE2[p0]) / (c1_0 * SUFD[p0] + c2_0 * PRED[p0]);
        res.y = (c1_1 * SUF1[p1] + c2_1 * PRE2[p1]) / (c1_1 * SUFD[p1] + c2_1 * PRED[p1]);
        res.z = (c1_2 * SUF1[p2] + c2_2 * PRE2[p2]) / (c1_2 * SUFD[p2] + c2_2 * PRED[p2]);
        res.w = (c1_3 * SUF1[p3] + c2_3 * PRE2[p3]) / (c1_3 * SUFD[p3] + c2_3 * PRED[p3]);
        *(float4*)(out + ((size_t)(b * F + f)) * N + t0) = res;
    }
}

// ---------------------------------------------------------------------------
extern "C" void kernel_launch(void* const* d_in, const int* in_sizes, int n_in,
                              void* d_out, int out_size, void* d_ws, size_t ws_size,
                              hipStream_t stream) {
    const float* x  = (const float*)d_in[0];
    const float* wk = (const float*)d_in[1];
    const float* wq = (const float*)d_in[2];
    float* out = (float*)d_out;

    // ws layout (u32 units): flags1[4*256]@0 | flags2[4*256]@1024 |
    //   done1[4*64]@2048 | done2[4*64]@2304 | pad | karr f32[BZ*N]@2624 |
    //   qkey u64[BZ*N]@19008 | pr u32[BZ*N]@51776   (all 16B-aligned)
    unsigned* wsu = (unsigned*)d_ws;
    unsigned* flags1 = wsu;
    unsigned* flags2 = wsu + 1024;
    unsigned* done1  = wsu + 2048;
    unsigned* done2  = wsu + 2304;
    float* karr = (float*)(wsu + 2624);
    unsigned long long* qkey = (unsigned long long*)(wsu + 19008);
    unsigned* prA = wsu + 51776;

    fused_gat<<<BZ * 64, 1024, 0, stream>>>(x, wk, wq, flags1, flags2,
                                            done1, done2, karr, qkey, prA, out);
}